// Round 1
// 3011.907 us; speedup vs baseline: 1.0627x; 1.0627x over previous
//
#include <hip/hip_runtime.h>
#include <hip/hip_bf16.h>
#include <stdint.h>

// Problem constants
#define B_ 8
#define H_ 512
#define F_ 256
#define P_ 12
#define M_ 4096          // B*H
#define K1_ 16384        // N*F = 64*256
#define J_ 1024          // 4*F

typedef __attribute__((ext_vector_type(8))) short short8;
typedef __attribute__((ext_vector_type(4))) float floatx4;

union FragU { uint4 u; short8 s; };

// Workspace layout (bytes)
#define OFF_W1H   ((size_t)0)          //  8,388,608  W1 swizzled bf16 hi
#define OFF_W1L   ((size_t)8388608)    //  8,388,608  W1 swizzled bf16 lo
#define OFF_WHSW  ((size_t)16777216)   //    524,288  Wh swizzled bf16
#define OFF_ENC   ((size_t)17301504)   //  4,194,304  encoder states fp32 [8][512][256]
#define OFF_C     ((size_t)21495808)   //      8,192  final c state [8][256]
#define OFF_XSUM  ((size_t)21504000)   //  4,194,304  xs transposed [256][4096]
#define OFF_XPRE  ((size_t)25698304)   // 16,777,216  Xpre [4096][1024]
#define OFF_P1    ((size_t)42475520)   // 33,554,432  split-K partials [8][256][4096]
// total ~76.0 MB

__device__ __forceinline__ unsigned short f2bf(float f) {
  uint32_t u = __float_as_uint(f);
  u += 0x7fffu + ((u >> 16) & 1u);
  return (unsigned short)(u >> 16);
}
__device__ __forceinline__ float bf2f(unsigned short h) {
  return __uint_as_float(((uint32_t)h) << 16);
}
__device__ __forceinline__ float sigm(float x) { return 1.f / (1.f + __expf(-x)); }
__device__ __forceinline__ float tanh_(float x) {
  float ax = fabsf(x);
  float e  = __expf(-2.f * ax);
  float t  = (1.f - e) / (1.f + e);
  return x < 0.f ? -t : t;
}

// Wave->tile mapping for the encoder: wave w, local tile i (0..15):
//   ZT = 16*(i>>2) + 4*w + (i&3)
// so wave w's tiles cover z-columns  256*g + [64w, 64w+64)  for each gate
// block g -- exactly the z values wave w's own gate threads (tid = 64w+lane)
// consume.  This makes the z hand-off intra-wave (no barrier needed).
#define ZT_OF(w, i) ((((i) >> 2) << 4) + ((w) << 2) + ((i) & 3))

// ---------------------------------------------------------------------------
// Prep: W1 -> bf16 hi/lo in MFMA A-fragment swizzled layout.
__global__ void k_prep_w1(const float* __restrict__ W1,
                          uint4* __restrict__ hi, uint4* __restrict__ lo) {
  int idx  = blockIdx.x * 1024 + threadIdx.x;     // 0..524287
  int lane = idx & 63;
  int kt   = (idx >> 6) & 511;
  int nt   = idx >> 15;                            // 0..15
  int n    = nt * 16 + (lane & 15);
  int kb   = kt * 32 + ((lane >> 4) << 3);
  unsigned short h8[8], l8[8];
#pragma unroll
  for (int j = 0; j < 8; ++j) {
    float v = W1[(size_t)(kb + j) * 256 + n];
    unsigned short hh = f2bf(v);
    h8[j] = hh;
    l8[j] = f2bf(v - bf2f(hh));
  }
  uint4 uh, ul;
  uh.x = (uint32_t)h8[0] | ((uint32_t)h8[1] << 16);
  uh.y = (uint32_t)h8[2] | ((uint32_t)h8[3] << 16);
  uh.z = (uint32_t)h8[4] | ((uint32_t)h8[5] << 16);
  uh.w = (uint32_t)h8[6] | ((uint32_t)h8[7] << 16);
  ul.x = (uint32_t)l8[0] | ((uint32_t)l8[1] << 16);
  ul.y = (uint32_t)l8[2] | ((uint32_t)l8[3] << 16);
  ul.z = (uint32_t)l8[4] | ((uint32_t)l8[5] << 16);
  ul.w = (uint32_t)l8[6] | ((uint32_t)l8[7] << 16);
  hi[idx] = uh;
  lo[idx] = ul;
}

// Wh -> bf16 swizzled A-fragments. Fragment (zt, kt): m = z col, k = h index.
// Linear: idx = (zt*8 + kt)*64 + lane
__global__ void k_prep_wh(const float* __restrict__ Wh, uint4* __restrict__ sw) {
  int idx  = blockIdx.x * 1024 + threadIdx.x;     // 0..32767
  int lane = idx & 63;
  int kt   = (idx >> 6) & 7;
  int zt   = idx >> 9;                             // 0..63
  int col  = zt * 16 + (lane & 15);
  int kb   = kt * 32 + ((lane >> 4) << 3);
  unsigned short h8[8];
#pragma unroll
  for (int j = 0; j < 8; ++j) h8[j] = f2bf(Wh[(size_t)(kb + j) * 1024 + col]);
  uint4 u;
  u.x = (uint32_t)h8[0] | ((uint32_t)h8[1] << 16);
  u.y = (uint32_t)h8[2] | ((uint32_t)h8[3] << 16);
  u.z = (uint32_t)h8[4] | ((uint32_t)h8[5] << 16);
  u.w = (uint32_t)h8[6] | ((uint32_t)h8[7] << 16);
  sw[idx] = u;
}

// ---------------------------------------------------------------------------
// GEMM1 split-K (unchanged)
__global__ __launch_bounds__(1024)
void k_gemm1(const float* __restrict__ x, const uint4* __restrict__ w1h,
             const uint4* __restrict__ w1l, float* __restrict__ P1) {
  __shared__ __align__(16) unsigned short xh[128 * 40];
  __shared__ __align__(16) unsigned short xl[128 * 40];
  int bm = blockIdx.x >> 3, kc = blockIdx.x & 7;
  int m0 = bm * 128, kcbase = kc * 2048;
  int tid = threadIdx.x, wave = tid >> 6, lane = tid & 63;
  int quad = lane >> 4, l15 = lane & 15;
  int srow = tid >> 3, skch = tid & 7;
  floatx4 acc[8];
#pragma unroll
  for (int mt = 0; mt < 8; ++mt) acc[mt] = (floatx4)(0.f);

  for (int it = 0; it < 64; ++it) {
    int kb = kcbase + it * 32;
    const float4 xv = *(const float4*)(x + (size_t)(m0 + srow) * K1_ + kb + skch * 4);
    unsigned short h0 = f2bf(xv.x), h1 = f2bf(xv.y), h2 = f2bf(xv.z), h3 = f2bf(xv.w);
    unsigned short g0 = f2bf(xv.x - bf2f(h0)), g1 = f2bf(xv.y - bf2f(h1));
    unsigned short g2 = f2bf(xv.z - bf2f(h2)), g3 = f2bf(xv.w - bf2f(h3));
    uint2 ph, pl;
    ph.x = (uint32_t)h0 | ((uint32_t)h1 << 16); ph.y = (uint32_t)h2 | ((uint32_t)h3 << 16);
    pl.x = (uint32_t)g0 | ((uint32_t)g1 << 16); pl.y = (uint32_t)g2 | ((uint32_t)g3 << 16);
    *(uint2*)&xh[srow * 40 + skch * 4] = ph;
    *(uint2*)&xl[srow * 40 + skch * 4] = pl;
    __syncthreads();

    size_t aoff = (size_t)(wave * 512 + kc * 64 + it) * 64 + lane;
    FragU ah; ah.u = w1h[aoff];
    FragU al; al.u = w1l[aoff];
#pragma unroll
    for (int mt = 0; mt < 8; ++mt) {
      FragU bh, bl;
      bh.u = *(const uint4*)&xh[(mt * 16 + l15) * 40 + quad * 8];
      bl.u = *(const uint4*)&xl[(mt * 16 + l15) * 40 + quad * 8];
      acc[mt] = __builtin_amdgcn_mfma_f32_16x16x32_bf16(ah.s, bh.s, acc[mt], 0, 0, 0);
      acc[mt] = __builtin_amdgcn_mfma_f32_16x16x32_bf16(ah.s, bl.s, acc[mt], 0, 0, 0);
      acc[mt] = __builtin_amdgcn_mfma_f32_16x16x32_bf16(al.s, bh.s, acc[mt], 0, 0, 0);
    }
    __syncthreads();
  }
  int nbase = wave * 16 + quad * 4;
#pragma unroll
  for (int mt = 0; mt < 8; ++mt) {
    int m = m0 + mt * 16 + l15;
#pragma unroll
    for (int r = 0; r < 4; ++r)
      P1[(size_t)(kc * 256 + nbase + r) * M_ + m] = acc[mt][r];
  }
}

// Sum split-K partials + b1 -> xsum[k][m]
__global__ void k_reduce(const float* __restrict__ P1, const float* __restrict__ b1,
                         float* __restrict__ xsum) {
  int idx = blockIdx.x * 1024 + threadIdx.x;       // 1,048,576
  int k = idx >> 12, m = idx & 4095;
  float s = b1[k];
#pragma unroll
  for (int kc = 0; kc < 8; ++kc) s += P1[(size_t)(kc * 256 + k) * M_ + m];
  xsum[(size_t)k * M_ + m] = s;
}

// GEMM2 (fp32 VALU, unchanged)
__global__ __launch_bounds__(256)
void k_gemm2(const float* __restrict__ xsum, const float* __restrict__ Wx,
             const float* __restrict__ bz, float* __restrict__ Xpre) {
  int m0 = blockIdx.x * 16;
  int j = threadIdx.x;
  float acc0[16], acc1[16], acc2[16], acc3[16];
  float bb0 = bz[j], bb1 = bz[256 + j], bb2 = bz[512 + j], bb3 = bz[768 + j];
#pragma unroll
  for (int mm = 0; mm < 16; ++mm) { acc0[mm] = bb0; acc1[mm] = bb1; acc2[mm] = bb2; acc3[mm] = bb3; }
  for (int k = 0; k < 256; ++k) {
    float w0 = Wx[(size_t)k * 1024 + j];
    float w1 = Wx[(size_t)k * 1024 + 256 + j];
    float w2 = Wx[(size_t)k * 1024 + 512 + j];
    float w3 = Wx[(size_t)k * 1024 + 768 + j];
#pragma unroll
    for (int mm = 0; mm < 16; ++mm) {
      float xv = xsum[(size_t)k * M_ + m0 + mm];
      acc0[mm] += xv * w0; acc1[mm] += xv * w1; acc2[mm] += xv * w2; acc3[mm] += xv * w3;
    }
  }
#pragma unroll
  for (int mm = 0; mm < 16; ++mm) {
    float* o = Xpre + (size_t)(m0 + mm) * 1024;
    o[j] = acc0[mm]; o[256 + j] = acc1[mm]; o[512 + j] = acc2[mm]; o[768 + j] = acc3[mm];
  }
}

// ---------------------------------------------------------------------------
// Encoder v3: one 256-thread block per batch; Wh fully resident.
//   - Wave-local tile mapping (ZT_OF): z hand-off is intra-wave -> ONE
//     __syncthreads per step (hb double-buffered).
//   - MFMA engine: 4 groups x 4 independent accumulators, kt-inner, so the
//     dependent-MFMA reuse distance is 4 instructions (pipelined issue), and
//     exec-masked z-stores happen only once per group (4 fences/step, not 32).
//   - LDS holds kt={6,7} fragments for ALL 16 tiles per wave; each group's
//     8 LDS frags are prefetched 24 MFMAs (~120cy) before use.
//   - wfr holds kt=0..5 for all 16 tiles: 96 uint4 = 384 regs.
//   - c state lives in a register (unit == tid).
__global__ __launch_bounds__(256, 1)
void k_encoder(const uint4* __restrict__ whsw, const float* __restrict__ Xpre,
               float* __restrict__ enc, float* __restrict__ cws) {
  __shared__ uint4 wl[8192];                          // 128 KB: kt 6..7 frags, all tiles
  __shared__ __align__(16) unsigned short hb[2][512]; // dbuf: [0..255]=h hi, [256..511]=h lo
  __shared__ __align__(16) float zsh[2048];           // [0..1023]=col0, [1024..2047]=col1
  int b = blockIdx.x, tid = threadIdx.x;
  int wave = tid >> 6, lane = tid & 63;
  int quad = lane >> 4, l15 = lane & 15;

  // stage wl: entry s (0..127): w = s>>5, i = (s>>1)&15, ktl = s&1
  {
    int grp = tid >> 6;
    for (int rep = 0; rep < 32; ++rep) {
      int s = rep * 4 + grp;
      int w = s >> 5, i = (s >> 1) & 15, ktl = s & 1;
      wl[s * 64 + lane] = whsw[(size_t)((ZT_OF(w, i) * 8 + 6 + ktl) * 64 + lane)];
    }
  }
  // register-resident frags: kt 0..5 for this wave's 16 tiles
  uint4 wfr[96];
#pragma unroll
  for (int i = 0; i < 16; ++i)
#pragma unroll
    for (int kt = 0; kt < 6; ++kt)
      wfr[i * 6 + kt] = whsw[(size_t)((ZT_OF(wave, i) * 8 + kt) * 64 + lane)];

  hb[0][tid] = 0; hb[0][256 + tid] = 0;
  hb[1][tid] = 0; hb[1][256 + tid] = 0;
  float creg = 0.f;
  const float* xpb = Xpre + (size_t)b * 512 * 1024;
  float xq0 = xpb[tid], xq1 = xpb[256 + tid], xq2 = xpb[512 + tid], xq3 = xpb[768 + tid];
  int hoff  = ((l15 == 1) ? 256 : 0) + quad * 8;       // hb read offset (shorts)
  int zwoff = ((l15 == 1) ? 1024 : 0) + quad * 4;      // zsh write base (floats)
  __syncthreads();

  int cur = 0;
  for (int t = 0; t < 512; ++t) {
    const unsigned short* hbc = hb[cur];
    // B frags: col0 = h_hi, col1 = h_lo (cols>=2 read hi, ignored)
    FragU bf[8];
#pragma unroll
    for (int kt = 0; kt < 8; ++kt)
      bf[kt].u = *(const uint4*)&hbc[hoff + kt * 32];
    // prefetch next Xpre row
    float nx0, nx1, nx2, nx3;
    if (t < 511) {
      const float* xp = xpb + (size_t)(t + 1) * 1024;
      nx0 = xp[tid]; nx1 = xp[256 + tid]; nx2 = xp[512 + tid]; nx3 = xp[768 + tid];
    } else { nx0 = nx1 = nx2 = nx3 = 0.f; }

#pragma unroll
    for (int g = 0; g < 4; ++g) {
      // prefetch this group's 8 LDS frags (kt 6,7 for tiles g*4..g*4+3)
      const uint4* wlg = wl + (size_t)(wave * 32 + g * 8) * 64 + lane;
      uint4 pf[8];
#pragma unroll
      for (int q = 0; q < 8; ++q) pf[q] = wlg[(size_t)q * 64];

      floatx4 a0 = (floatx4)(0.f), a1 = (floatx4)(0.f);
      floatx4 a2 = (floatx4)(0.f), a3 = (floatx4)(0.f);
#pragma unroll
      for (int kt = 0; kt < 6; ++kt) {
        FragU f0, f1, f2, f3;
        f0.u = wfr[(g * 4 + 0) * 6 + kt];
        f1.u = wfr[(g * 4 + 1) * 6 + kt];
        f2.u = wfr[(g * 4 + 2) * 6 + kt];
        f3.u = wfr[(g * 4 + 3) * 6 + kt];
        a0 = __builtin_amdgcn_mfma_f32_16x16x32_bf16(f0.s, bf[kt].s, a0, 0, 0, 0);
        a1 = __builtin_amdgcn_mfma_f32_16x16x32_bf16(f1.s, bf[kt].s, a1, 0, 0, 0);
        a2 = __builtin_amdgcn_mfma_f32_16x16x32_bf16(f2.s, bf[kt].s, a2, 0, 0, 0);
        a3 = __builtin_amdgcn_mfma_f32_16x16x32_bf16(f3.s, bf[kt].s, a3, 0, 0, 0);
      }
      {
        FragU p0, p1, p2, p3;
        p0.u = pf[0]; p1.u = pf[2]; p2.u = pf[4]; p3.u = pf[6];
        a0 = __builtin_amdgcn_mfma_f32_16x16x32_bf16(p0.s, bf[6].s, a0, 0, 0, 0);
        a1 = __builtin_amdgcn_mfma_f32_16x16x32_bf16(p1.s, bf[6].s, a1, 0, 0, 0);
        a2 = __builtin_amdgcn_mfma_f32_16x16x32_bf16(p2.s, bf[6].s, a2, 0, 0, 0);
        a3 = __builtin_amdgcn_mfma_f32_16x16x32_bf16(p3.s, bf[6].s, a3, 0, 0, 0);
        p0.u = pf[1]; p1.u = pf[3]; p2.u = pf[5]; p3.u = pf[7];
        a0 = __builtin_amdgcn_mfma_f32_16x16x32_bf16(p0.s, bf[7].s, a0, 0, 0, 0);
        a1 = __builtin_amdgcn_mfma_f32_16x16x32_bf16(p1.s, bf[7].s, a1, 0, 0, 0);
        a2 = __builtin_amdgcn_mfma_f32_16x16x32_bf16(p2.s, bf[7].s, a2, 0, 0, 0);
        a3 = __builtin_amdgcn_mfma_f32_16x16x32_bf16(p3.s, bf[7].s, a3, 0, 0, 0);
      }
      if (l15 < 2) {   // single branch per group; ZT = 16*g + 4*wave + j
        int zb = zwoff + (16 * g + 4 * wave) * 16;
        *(floatx4*)&zsh[zb +  0] = a0;
        *(floatx4*)&zsh[zb + 16] = a1;
        *(floatx4*)&zsh[zb + 32] = a2;
        *(floatx4*)&zsh[zb + 48] = a3;
      }
    }

    // gates: z written by this thread's own wave (intra-wave LDS ordering)
    float zi = zsh[tid]       + zsh[1024 + tid]       + xq0;
    float zf = zsh[256 + tid] + zsh[1024 + 256 + tid] + xq1;
    float zg = zsh[512 + tid] + zsh[1024 + 512 + tid] + xq2;
    float zo = zsh[768 + tid] + zsh[1024 + 768 + tid] + xq3;
    float ig = sigm(zi), fg = sigm(zf), gg = tanh_(zg), og = sigm(zo);
    float cn = fg * creg + ig * gg;
    creg = cn;
    float hn = og * tanh_(cn);
    enc[((size_t)b * 512 + t) * 256 + tid] = hn;
    unsigned short hh = f2bf(hn);
    int nxt = cur ^ 1;
    hb[nxt][tid] = hh;
    hb[nxt][256 + tid] = f2bf(hn - bf2f(hh));
    __syncthreads();      // hb[nxt] visible to all waves; zsh/c are wave/thread-local
    cur = nxt;
    xq0 = nx0; xq1 = nx1; xq2 = nx2; xq3 = nx3;
  }
  cws[b * 256 + tid] = creg;
}

// ---------------------------------------------------------------------------
// Decoder (round-1 structure; unroll pragmas on the serial GEMV loops)
__global__ __launch_bounds__(1024)
void k_decoder(const float* __restrict__ enc, const float* __restrict__ cws,
               const float* __restrict__ Wx, const float* __restrict__ Wh,
               const float* __restrict__ bz, const float* __restrict__ Wa,
               const float* __restrict__ ba, const float* __restrict__ W2,
               const float* __restrict__ b2, float* __restrict__ out) {
  __shared__ float h[256], c[256], q[256], ctx[256];
  __shared__ float sc[512];
  __shared__ float zb[1024];
  __shared__ float smx[2];
  int b = blockIdx.x, tid = threadIdx.x;
  int wave = tid >> 6, lane = tid & 63;
  const float* encb = enc + (size_t)b * 512 * 256;
  if (tid < 256) { h[tid] = encb[(size_t)511 * 256 + tid]; c[tid] = cws[b * 256 + tid]; }
  __syncthreads();

  for (int p = 0; p < 12; ++p) {
    {
      int j = tid & 255, ks = tid >> 8;
      float s = 0.f;
#pragma unroll 8
      for (int kk = 0; kk < 64; ++kk) {
        int k = ks * 64 + kk;
        s += h[k] * Wa[(size_t)k * 256 + j];
      }
      zb[tid] = s;
    }
    __syncthreads();
    if (tid < 256) q[tid] = ba[tid] + zb[tid] + zb[256 + tid] + zb[512 + tid] + zb[768 + tid];
    __syncthreads();
    {
      float4 qv = *(const float4*)&q[lane * 4];
      for (int r = 0; r < 32; ++r) {
        int hh = wave * 32 + r;
        const float4 ev = *(const float4*)(encb + (size_t)hh * 256 + lane * 4);
        float s = ev.x * qv.x + ev.y * qv.y + ev.z * qv.z + ev.w * qv.w;
#pragma unroll
        for (int off = 32; off >= 1; off >>= 1) s += __shfl_xor(s, off, 64);
        if (lane == 0) sc[hh] = s;
      }
    }
    __syncthreads();
    if (tid < 64) {
      float m = -3.4e38f;
      for (int r = 0; r < 8; ++r) m = fmaxf(m, sc[tid * 8 + r]);
#pragma unroll
      for (int off = 32; off >= 1; off >>= 1) m = fmaxf(m, __shfl_xor(m, off, 64));
      if (tid == 0) smx[0] = m;
    }
    __syncthreads();
    if (tid < 512) sc[tid] = __expf(sc[tid] - smx[0]);
    __syncthreads();
    if (tid < 64) {
      float s = 0.f;
      for (int r = 0; r < 8; ++r) s += sc[tid * 8 + r];
#pragma unroll
      for (int off = 32; off >= 1; off >>= 1) s += __shfl_xor(s, off, 64);
      if (tid == 0) smx[1] = 1.f / s;
    }
    __syncthreads();
    {
      int k = tid & 255, hs = tid >> 8;
      float s = 0.f;
#pragma unroll 8
      for (int r = 0; r < 128; ++r) {
        int hh = hs * 128 + r;
        s += sc[hh] * encb[(size_t)hh * 256 + k];
      }
      zb[tid] = s;
    }
    __syncthreads();
    if (tid < 256) ctx[tid] = (zb[tid] + zb[256 + tid] + zb[512 + tid] + zb[768 + tid]) * smx[1];
    __syncthreads();
    {
      float s = bz[tid];
#pragma unroll 8
      for (int k = 0; k < 256; ++k) {
        s += ctx[k] * Wx[(size_t)k * 1024 + tid] + h[k] * Wh[(size_t)k * 1024 + tid];
      }
      zb[tid] = s;
    }
    __syncthreads();
    if (tid < 256) {
      float zi = zb[tid], zf = zb[256 + tid], zg = zb[512 + tid], zo = zb[768 + tid];
      float ig = sigm(zi), fg = sigm(zf), gg = tanh_(zg), og = sigm(zo);
      float cn = fg * c[tid] + ig * gg;
      c[tid] = cn;
      h[tid] = og * tanh_(cn);
    }
    __syncthreads();
    if (tid < 64) {
      float s = b2[tid];
#pragma unroll 8
      for (int f = 0; f < 256; ++f) s += h[f] * W2[(size_t)f * 64 + tid];
      out[((size_t)b * 12 + p) * 64 + tid] = s;
    }
    __syncthreads();
  }
}

// ---------------------------------------------------------------------------
extern "C" void kernel_launch(void* const* d_in, const int* in_sizes, int n_in,
                              void* d_out, int out_size, void* d_ws, size_t ws_size,
                              hipStream_t stream) {
  const float* x  = (const float*)d_in[0];
  const float* W1 = (const float*)d_in[1];
  const float* b1 = (const float*)d_in[2];
  const float* Wx = (const float*)d_in[3];
  const float* Wh = (const float*)d_in[4];
  const float* bz = (const float*)d_in[5];
  const float* Wa = (const float*)d_in[6];
  const float* ba = (const float*)d_in[7];
  const float* W2 = (const float*)d_in[8];
  const float* b2 = (const float*)d_in[9];

  char* ws = (char*)d_ws;
  uint4* w1h  = (uint4*)(ws + OFF_W1H);
  uint4* w1l  = (uint4*)(ws + OFF_W1L);
  uint4* whsw = (uint4*)(ws + OFF_WHSW);
  float* enc  = (float*)(ws + OFF_ENC);
  float* cws  = (float*)(ws + OFF_C);
  float* xsum = (float*)(ws + OFF_XSUM);
  float* xpre = (float*)(ws + OFF_XPRE);
  float* p1   = (float*)(ws + OFF_P1);

  k_prep_w1<<<dim3(512), dim3(1024), 0, stream>>>(W1, w1h, w1l);
  k_prep_wh<<<dim3(32), dim3(1024), 0, stream>>>(Wh, whsw);
  k_gemm1<<<dim3(256), dim3(1024), 0, stream>>>(x, w1h, w1l, p1);
  k_reduce<<<dim3(1024), dim3(1024), 0, stream>>>(p1, b1, xsum);
  k_gemm2<<<dim3(256), dim3(256), 0, stream>>>(xsum, Wx, bz, xpre);
  k_encoder<<<dim3(8), dim3(256), 0, stream>>>(whsw, xpre, enc, cws);
  k_decoder<<<dim3(8), dim3(1024), 0, stream>>>(enc, cws, Wx, Wh, bz, Wa, ba, W2, b2,
                                                (float*)d_out);
}

// Round 2
// 2699.213 us; speedup vs baseline: 1.1858x; 1.1158x over previous
//
#include <hip/hip_runtime.h>
#include <hip/hip_bf16.h>
#include <stdint.h>

// Problem constants
#define B_ 8
#define H_ 512
#define F_ 256
#define P_ 12
#define M_ 4096          // B*H
#define K1_ 16384        // N*F = 64*256
#define J_ 1024          // 4*F

typedef __attribute__((ext_vector_type(8))) short short8;
typedef __attribute__((ext_vector_type(4))) float floatx4;

union FragU { uint4 u; short8 s; };

// Workspace layout (bytes)
#define OFF_W1H   ((size_t)0)          //  8,388,608  W1 swizzled bf16 hi
#define OFF_W1L   ((size_t)8388608)    //  8,388,608  W1 swizzled bf16 lo
#define OFF_WHSW  ((size_t)16777216)   //    524,288  Wh swizzled bf16
#define OFF_ENC   ((size_t)17301504)   //  4,194,304  encoder states fp32 [8][512][256]
#define OFF_C     ((size_t)21495808)   //      8,192  final c state [8][256]
#define OFF_XSUM  ((size_t)21504000)   //  4,194,304  xs transposed [256][4096]
#define OFF_XPRE  ((size_t)25698304)   // 16,777,216  Xpre [4096][1024]
#define OFF_P1    ((size_t)42475520)   // 33,554,432  split-K partials [8][256][4096]
// total ~76.0 MB

__device__ __forceinline__ unsigned short f2bf(float f) {
  uint32_t u = __float_as_uint(f);
  u += 0x7fffu + ((u >> 16) & 1u);
  return (unsigned short)(u >> 16);
}
__device__ __forceinline__ float bf2f(unsigned short h) {
  return __uint_as_float(((uint32_t)h) << 16);
}
__device__ __forceinline__ float sigm(float x) { return 1.f / (1.f + __expf(-x)); }
__device__ __forceinline__ float tanh_(float x) {
  float ax = fabsf(x);
  float e  = __expf(-2.f * ax);
  float t  = (1.f - e) / (1.f + e);
  return x < 0.f ? -t : t;
}

// ---------------------------------------------------------------------------
// Prep: W1 -> bf16 hi/lo in MFMA A-fragment swizzled layout.
__global__ void k_prep_w1(const float* __restrict__ W1,
                          uint4* __restrict__ hi, uint4* __restrict__ lo) {
  int idx  = blockIdx.x * 1024 + threadIdx.x;     // 0..524287
  int lane = idx & 63;
  int kt   = (idx >> 6) & 511;
  int nt   = idx >> 15;                            // 0..15
  int n    = nt * 16 + (lane & 15);
  int kb   = kt * 32 + ((lane >> 4) << 3);
  unsigned short h8[8], l8[8];
#pragma unroll
  for (int j = 0; j < 8; ++j) {
    float v = W1[(size_t)(kb + j) * 256 + n];
    unsigned short hh = f2bf(v);
    h8[j] = hh;
    l8[j] = f2bf(v - bf2f(hh));
  }
  uint4 uh, ul;
  uh.x = (uint32_t)h8[0] | ((uint32_t)h8[1] << 16);
  uh.y = (uint32_t)h8[2] | ((uint32_t)h8[3] << 16);
  uh.z = (uint32_t)h8[4] | ((uint32_t)h8[5] << 16);
  uh.w = (uint32_t)h8[6] | ((uint32_t)h8[7] << 16);
  ul.x = (uint32_t)l8[0] | ((uint32_t)l8[1] << 16);
  ul.y = (uint32_t)l8[2] | ((uint32_t)l8[3] << 16);
  ul.z = (uint32_t)l8[4] | ((uint32_t)l8[5] << 16);
  ul.w = (uint32_t)l8[6] | ((uint32_t)l8[7] << 16);
  hi[idx] = uh;
  lo[idx] = ul;
}

// Wh -> bf16 swizzled A-fragments. Fragment (zt, kt): m = z col, k = h index.
// Linear: idx = (zt*8 + kt)*64 + lane
__global__ void k_prep_wh(const float* __restrict__ Wh, uint4* __restrict__ sw) {
  int idx  = blockIdx.x * 1024 + threadIdx.x;     // 0..32767
  int lane = idx & 63;
  int kt   = (idx >> 6) & 7;
  int zt   = idx >> 9;                             // 0..63
  int col  = zt * 16 + (lane & 15);
  int kb   = kt * 32 + ((lane >> 4) << 3);
  unsigned short h8[8];
#pragma unroll
  for (int j = 0; j < 8; ++j) h8[j] = f2bf(Wh[(size_t)(kb + j) * 1024 + col]);
  uint4 u;
  u.x = (uint32_t)h8[0] | ((uint32_t)h8[1] << 16);
  u.y = (uint32_t)h8[2] | ((uint32_t)h8[3] << 16);
  u.z = (uint32_t)h8[4] | ((uint32_t)h8[5] << 16);
  u.w = (uint32_t)h8[6] | ((uint32_t)h8[7] << 16);
  sw[idx] = u;
}

// ---------------------------------------------------------------------------
// GEMM1 split-K; x-load prefetched one iteration ahead so HBM latency hides
// under the MFMA phase instead of sitting exposed before the barrier.
__global__ __launch_bounds__(1024)
void k_gemm1(const float* __restrict__ x, const uint4* __restrict__ w1h,
             const uint4* __restrict__ w1l, float* __restrict__ P1) {
  __shared__ __align__(16) unsigned short xh[128 * 40];
  __shared__ __align__(16) unsigned short xl[128 * 40];
  int bm = blockIdx.x >> 3, kc = blockIdx.x & 7;
  int m0 = bm * 128, kcbase = kc * 2048;
  int tid = threadIdx.x, wave = tid >> 6, lane = tid & 63;
  int quad = lane >> 4, l15 = lane & 15;
  int srow = tid >> 3, skch = tid & 7;
  floatx4 acc[8];
#pragma unroll
  for (int mt = 0; mt < 8; ++mt) acc[mt] = (floatx4)(0.f);

  const float* xrow = x + (size_t)(m0 + srow) * K1_ + kcbase + skch * 4;
  float4 xv = *(const float4*)(xrow);
  for (int it = 0; it < 64; ++it) {
    unsigned short h0 = f2bf(xv.x), h1 = f2bf(xv.y), h2 = f2bf(xv.z), h3 = f2bf(xv.w);
    unsigned short g0 = f2bf(xv.x - bf2f(h0)), g1 = f2bf(xv.y - bf2f(h1));
    unsigned short g2 = f2bf(xv.z - bf2f(h2)), g3 = f2bf(xv.w - bf2f(h3));
    uint2 ph, pl;
    ph.x = (uint32_t)h0 | ((uint32_t)h1 << 16); ph.y = (uint32_t)h2 | ((uint32_t)h3 << 16);
    pl.x = (uint32_t)g0 | ((uint32_t)g1 << 16); pl.y = (uint32_t)g2 | ((uint32_t)g3 << 16);
    *(uint2*)&xh[srow * 40 + skch * 4] = ph;
    *(uint2*)&xl[srow * 40 + skch * 4] = pl;
    __syncthreads();

    float4 xn = xv;
    if (it < 63) xn = *(const float4*)(xrow + (it + 1) * 32);

    size_t aoff = (size_t)(wave * 512 + kc * 64 + it) * 64 + lane;
    FragU ah; ah.u = w1h[aoff];
    FragU al; al.u = w1l[aoff];
#pragma unroll
    for (int mt = 0; mt < 8; ++mt) {
      FragU bh, bl;
      bh.u = *(const uint4*)&xh[(mt * 16 + l15) * 40 + quad * 8];
      bl.u = *(const uint4*)&xl[(mt * 16 + l15) * 40 + quad * 8];
      acc[mt] = __builtin_amdgcn_mfma_f32_16x16x32_bf16(ah.s, bh.s, acc[mt], 0, 0, 0);
      acc[mt] = __builtin_amdgcn_mfma_f32_16x16x32_bf16(ah.s, bl.s, acc[mt], 0, 0, 0);
      acc[mt] = __builtin_amdgcn_mfma_f32_16x16x32_bf16(al.s, bh.s, acc[mt], 0, 0, 0);
    }
    __syncthreads();
    xv = xn;
  }
  int nbase = wave * 16 + quad * 4;
#pragma unroll
  for (int mt = 0; mt < 8; ++mt) {
    int m = m0 + mt * 16 + l15;
#pragma unroll
    for (int r = 0; r < 4; ++r)
      P1[(size_t)(kc * 256 + nbase + r) * M_ + m] = acc[mt][r];
  }
}

// Sum split-K partials + b1 -> xsum[k][m]
__global__ void k_reduce(const float* __restrict__ P1, const float* __restrict__ b1,
                         float* __restrict__ xsum) {
  int idx = blockIdx.x * 1024 + threadIdx.x;       // 1,048,576
  int k = idx >> 12, m = idx & 4095;
  float s = b1[k];
#pragma unroll
  for (int kc = 0; kc < 8; ++kc) s += P1[(size_t)(kc * 256 + k) * M_ + m];
  xsum[(size_t)k * M_ + m] = s;
}

// GEMM2 (fp32 VALU)
__global__ __launch_bounds__(256)
void k_gemm2(const float* __restrict__ xsum, const float* __restrict__ Wx,
             const float* __restrict__ bz, float* __restrict__ Xpre) {
  int m0 = blockIdx.x * 16;
  int j = threadIdx.x;
  float acc0[16], acc1[16], acc2[16], acc3[16];
  float bb0 = bz[j], bb1 = bz[256 + j], bb2 = bz[512 + j], bb3 = bz[768 + j];
#pragma unroll
  for (int mm = 0; mm < 16; ++mm) { acc0[mm] = bb0; acc1[mm] = bb1; acc2[mm] = bb2; acc3[mm] = bb3; }
#pragma unroll 4
  for (int k = 0; k < 256; ++k) {
    float w0 = Wx[(size_t)k * 1024 + j];
    float w1 = Wx[(size_t)k * 1024 + 256 + j];
    float w2 = Wx[(size_t)k * 1024 + 512 + j];
    float w3 = Wx[(size_t)k * 1024 + 768 + j];
#pragma unroll
    for (int mm = 0; mm < 16; ++mm) {
      float xv = xsum[(size_t)k * M_ + m0 + mm];
      acc0[mm] += xv * w0; acc1[mm] += xv * w1; acc2[mm] += xv * w2; acc3[mm] += xv * w3;
    }
  }
#pragma unroll
  for (int mm = 0; mm < 16; ++mm) {
    float* o = Xpre + (size_t)(m0 + mm) * 1024;
    o[j] = acc0[mm]; o[256 + j] = acc1[mm]; o[512 + j] = acc2[mm]; o[768 + j] = acc3[mm];
  }
}

// ---------------------------------------------------------------------------
// Encoder v4: 512 threads (8 waves, 2 waves/SIMD) per batch.
//   - Per-wave VGPR budget <=256 by design (48 weight frags = 192 regs), so
//     the compiler can actually keep weights resident (v3 needed 384+ and
//     spilled: VGPR_Count=232 with massive accvgpr/scratch traffic).
//   - Wave w owns 8 z-tiles {16g + 2w + p : g in 0..3, p in 0..1}; the gate
//     threads of wave w (units j = tid>>1 in [32w,32w+32)) consume exactly
//     those z columns -> z hand-off intra-wave, ONE barrier per step.
//   - Per group of 4 tiles: 3 tiles' weights from registers, 1 tile streamed
//     from LDS (one frag per kt, 3-deep pipeline: smooth LDS pressure).
//   - Gates paired even/odd lanes via shfl_xor(1); c duplicated in the pair.
__global__ __launch_bounds__(512, 2)
void k_encoder(const uint4* __restrict__ whsw, const float* __restrict__ Xpre,
               float* __restrict__ enc, float* __restrict__ cws) {
  __shared__ uint4 wl[8192];                          // 128 KB: LDS-streamed weight tiles
  __shared__ __align__(16) unsigned short hb[2][512]; // dbuf: [0..255]=h hi, [256..511]=h lo
  __shared__ __align__(16) float zsh[2048];           // [0..1023]=hi-prod, [1024..2047]=lo-prod
  int b = blockIdx.x, tid = threadIdx.x;
  int wave = tid >> 6, lane = tid & 63;
  int quad = lane >> 4, l15 = lane & 15;
  int e = tid & 1, j = tid >> 1;

  // stage wl: frag f = w*16 + G*8 + kt  (the group's i=3 tile, all 8 kt)
  for (int r = 0; r < 16; ++r) {
    int u = r * 512 + tid;                 // 0..8191
    int ln = u & 63, fr = u >> 6;
    int w = fr >> 4, G = (fr >> 3) & 1, kt = fr & 7;
    int zt = 16 * (2 * G + 1) + 2 * w + 1; // tile i=3 of group G
    wl[u] = whsw[(size_t)((zt * 8 + kt) * 64 + ln)];
  }
  // register-resident weights: tiles i=0..2 of each group, all 8 kt
  uint4 wfr[48];
#pragma unroll
  for (int G = 0; G < 2; ++G)
#pragma unroll
    for (int i = 0; i < 3; ++i) {
      int zt = 16 * (2 * G + (i >> 1)) + 2 * wave + (i & 1);
#pragma unroll
      for (int kt = 0; kt < 8; ++kt)
        wfr[(G * 3 + i) * 8 + kt] = whsw[(size_t)((zt * 8 + kt) * 64 + lane)];
    }

  hb[0][tid] = 0; hb[1][tid] = 0;
  float c_ = 0.f;
  const float* xpb = Xpre + (size_t)b * 512 * 1024;
  int colA = 256 * e + j;        // e=0: i-gate col j   ; e=1: f-gate col 256+j
  int colB = 512 + colA;         // e=0: g-gate col 512+j; e=1: o-gate col 768+j
  int hoff  = ((l15 == 1) ? 256 : 0) + quad * 8;   // hb read offset (shorts)
  int zwoff = ((l15 == 1) ? 1024 : 0) + quad * 4;  // zsh write base (floats)
  __syncthreads();

  int cur = 0;
  for (int t = 0; t < 512; ++t) {
    const unsigned short* hbc = hb[cur];
    // this step's gate inputs: issue early, consumed after MFMA phase
    float xA = xpb[(size_t)t * 1024 + colA];
    float xB = xpb[(size_t)t * 1024 + colB];

#pragma unroll
    for (int G = 0; G < 2; ++G) {
      const uint4* wlg = wl + (size_t)((wave * 2 + G) * 8) * 64 + lane;
      FragU bfr[8], pfr[8];
#pragma unroll
      for (int k = 0; k < 3; ++k) {
        bfr[k].u = *(const uint4*)&hbc[hoff + k * 32];
        pfr[k].u = wlg[(size_t)k * 64];
      }
      floatx4 a0 = (floatx4)(0.f), a1 = (floatx4)(0.f);
      floatx4 a2 = (floatx4)(0.f), a3 = (floatx4)(0.f);
#pragma unroll
      for (int kt = 0; kt < 8; ++kt) {
        if (kt < 5) {
          bfr[kt + 3].u = *(const uint4*)&hbc[hoff + (kt + 3) * 32];
          pfr[kt + 3].u = wlg[(size_t)(kt + 3) * 64];
        }
        FragU f0, f1, f2;
        f0.u = wfr[(G * 3 + 0) * 8 + kt];
        f1.u = wfr[(G * 3 + 1) * 8 + kt];
        f2.u = wfr[(G * 3 + 2) * 8 + kt];
        a0 = __builtin_amdgcn_mfma_f32_16x16x32_bf16(f0.s, bfr[kt].s, a0, 0, 0, 0);
        a1 = __builtin_amdgcn_mfma_f32_16x16x32_bf16(f1.s, bfr[kt].s, a1, 0, 0, 0);
        a2 = __builtin_amdgcn_mfma_f32_16x16x32_bf16(f2.s, bfr[kt].s, a2, 0, 0, 0);
        a3 = __builtin_amdgcn_mfma_f32_16x16x32_bf16(pfr[kt].s, bfr[kt].s, a3, 0, 0, 0);
      }
      if (l15 < 2) {
        int zt0 = 16 * (2 * G) + 2 * wave;       // i=0
        int zt2 = 16 * (2 * G + 1) + 2 * wave;   // i=2
        *(floatx4*)&zsh[zwoff + zt0 * 16]        = a0;
        *(floatx4*)&zsh[zwoff + (zt0 + 1) * 16]  = a1;
        *(floatx4*)&zsh[zwoff + zt2 * 16]        = a2;
        *(floatx4*)&zsh[zwoff + (zt2 + 1) * 16]  = a3;
      }
    }

    // gates: paired even/odd lanes; z came from this wave's own tiles
    float zA = zsh[colA] + zsh[1024 + colA] + xA;
    float zB = zsh[colB] + zsh[1024 + colB] + xB;
    float actA = sigm(zA);                       // i (even) / f (odd)
    float tnh = tanh_(zB), sg = sigm(zB);
    float actB = e ? sg : tnh;                   // g (even) / o (odd)
    float p = actA * actB;                       // even: i*g
    float send = e ? actA : p;                   // odd sends f; even sends i*g
    float recv = __shfl_xor(send, 1, 64);
    float cn = e ? (actA * c_ + recv)            // odd : f*c + (i*g)
                 : (recv * c_ + p);              // even: f*c + (i*g)
    c_ = cn;
    float th = tanh_(cn);
    float hn = actB * th;                        // odd: o*tanh(c) (even: junk)
    int nxt = cur ^ 1;
    if (e) {
      enc[((size_t)b * 512 + t) * 256 + j] = hn;
      unsigned short hh = f2bf(hn);
      hb[nxt][j] = hh;
      hb[nxt][256 + j] = f2bf(hn - bf2f(hh));
    }
    __syncthreads();      // hb[nxt] visible to all waves before next step
    cur = nxt;
  }
  if (e) cws[b * 256 + j] = c_;
}

// ---------------------------------------------------------------------------
// Decoder (unchanged)
__global__ __launch_bounds__(1024)
void k_decoder(const float* __restrict__ enc, const float* __restrict__ cws,
               const float* __restrict__ Wx, const float* __restrict__ Wh,
               const float* __restrict__ bz, const float* __restrict__ Wa,
               const float* __restrict__ ba, const float* __restrict__ W2,
               const float* __restrict__ b2, float* __restrict__ out) {
  __shared__ float h[256], c[256], q[256], ctx[256];
  __shared__ float sc[512];
  __shared__ float zb[1024];
  __shared__ float smx[2];
  int b = blockIdx.x, tid = threadIdx.x;
  int wave = tid >> 6, lane = tid & 63;
  const float* encb = enc + (size_t)b * 512 * 256;
  if (tid < 256) { h[tid] = encb[(size_t)511 * 256 + tid]; c[tid] = cws[b * 256 + tid]; }
  __syncthreads();

  for (int p = 0; p < 12; ++p) {
    {
      int j = tid & 255, ks = tid >> 8;
      float s = 0.f;
#pragma unroll 8
      for (int kk = 0; kk < 64; ++kk) {
        int k = ks * 64 + kk;
        s += h[k] * Wa[(size_t)k * 256 + j];
      }
      zb[tid] = s;
    }
    __syncthreads();
    if (tid < 256) q[tid] = ba[tid] + zb[tid] + zb[256 + tid] + zb[512 + tid] + zb[768 + tid];
    __syncthreads();
    {
      float4 qv = *(const float4*)&q[lane * 4];
      for (int r = 0; r < 32; ++r) {
        int hh = wave * 32 + r;
        const float4 ev = *(const float4*)(encb + (size_t)hh * 256 + lane * 4);
        float s = ev.x * qv.x + ev.y * qv.y + ev.z * qv.z + ev.w * qv.w;
#pragma unroll
        for (int off = 32; off >= 1; off >>= 1) s += __shfl_xor(s, off, 64);
        if (lane == 0) sc[hh] = s;
      }
    }
    __syncthreads();
    if (tid < 64) {
      float m = -3.4e38f;
      for (int r = 0; r < 8; ++r) m = fmaxf(m, sc[tid * 8 + r]);
#pragma unroll
      for (int off = 32; off >= 1; off >>= 1) m = fmaxf(m, __shfl_xor(m, off, 64));
      if (tid == 0) smx[0] = m;
    }
    __syncthreads();
    if (tid < 512) sc[tid] = __expf(sc[tid] - smx[0]);
    __syncthreads();
    if (tid < 64) {
      float s = 0.f;
      for (int r = 0; r < 8; ++r) s += sc[tid * 8 + r];
#pragma unroll
      for (int off = 32; off >= 1; off >>= 1) s += __shfl_xor(s, off, 64);
      if (tid == 0) smx[1] = 1.f / s;
    }
    __syncthreads();
    {
      int k = tid & 255, hs = tid >> 8;
      float s = 0.f;
#pragma unroll 8
      for (int r = 0; r < 128; ++r) {
        int hh = hs * 128 + r;
        s += sc[hh] * encb[(size_t)hh * 256 + k];
      }
      zb[tid] = s;
    }
    __syncthreads();
    if (tid < 256) ctx[tid] = (zb[tid] + zb[256 + tid] + zb[512 + tid] + zb[768 + tid]) * smx[1];
    __syncthreads();
    {
      float s = bz[tid];
#pragma unroll 8
      for (int k = 0; k < 256; ++k) {
        s += ctx[k] * Wx[(size_t)k * 1024 + tid] + h[k] * Wh[(size_t)k * 1024 + tid];
      }
      zb[tid] = s;
    }
    __syncthreads();
    if (tid < 256) {
      float zi = zb[tid], zf = zb[256 + tid], zg = zb[512 + tid], zo = zb[768 + tid];
      float ig = sigm(zi), fg = sigm(zf), gg = tanh_(zg), og = sigm(zo);
      float cn = fg * c[tid] + ig * gg;
      c[tid] = cn;
      h[tid] = og * tanh_(cn);
    }
    __syncthreads();
    if (tid < 64) {
      float s = b2[tid];
#pragma unroll 8
      for (int f = 0; f < 256; ++f) s += h[f] * W2[(size_t)f * 64 + tid];
      out[((size_t)b * 12 + p) * 64 + tid] = s;
    }
    __syncthreads();
  }
}

// ---------------------------------------------------------------------------
extern "C" void kernel_launch(void* const* d_in, const int* in_sizes, int n_in,
                              void* d_out, int out_size, void* d_ws, size_t ws_size,
                              hipStream_t stream) {
  const float* x  = (const float*)d_in[0];
  const float* W1 = (const float*)d_in[1];
  const float* b1 = (const float*)d_in[2];
  const float* Wx = (const float*)d_in[3];
  const float* Wh = (const float*)d_in[4];
  const float* bz = (const float*)d_in[5];
  const float* Wa = (const float*)d_in[6];
  const float* ba = (const float*)d_in[7];
  const float* W2 = (const float*)d_in[8];
  const float* b2 = (const float*)d_in[9];

  char* ws = (char*)d_ws;
  uint4* w1h  = (uint4*)(ws + OFF_W1H);
  uint4* w1l  = (uint4*)(ws + OFF_W1L);
  uint4* whsw = (uint4*)(ws + OFF_WHSW);
  float* enc  = (float*)(ws + OFF_ENC);
  float* cws  = (float*)(ws + OFF_C);
  float* xsum = (float*)(ws + OFF_XSUM);
  float* xpre = (float*)(ws + OFF_XPRE);
  float* p1   = (float*)(ws + OFF_P1);

  k_prep_w1<<<dim3(512), dim3(1024), 0, stream>>>(W1, w1h, w1l);
  k_prep_wh<<<dim3(32), dim3(1024), 0, stream>>>(Wh, whsw);
  k_gemm1<<<dim3(256), dim3(1024), 0, stream>>>(x, w1h, w1l, p1);
  k_reduce<<<dim3(1024), dim3(1024), 0, stream>>>(p1, b1, xsum);
  k_gemm2<<<dim3(256), dim3(256), 0, stream>>>(xsum, Wx, bz, xpre);
  k_encoder<<<dim3(8), dim3(512), 0, stream>>>(whsw, xpre, enc, cws);
  k_decoder<<<dim3(8), dim3(1024), 0, stream>>>(enc, cws, Wx, Wh, bz, Wa, ba, W2, b2,
                                                (float*)d_out);
}

// Round 3
// 1988.656 us; speedup vs baseline: 1.6095x; 1.3573x over previous
//
#include <hip/hip_runtime.h>
#include <hip/hip_bf16.h>
#include <stdint.h>

// Problem constants
#define B_ 8
#define H_ 512
#define F_ 256
#define P_ 12
#define M_ 4096          // B*H
#define K1_ 16384        // N*F = 64*256
#define J_ 1024          // 4*F

typedef __attribute__((ext_vector_type(8))) short short8;
typedef __attribute__((ext_vector_type(4))) float floatx4;

union FragU { uint4 u; short8 s; };

// Workspace layout (bytes)
#define OFF_W1H   ((size_t)0)          //  8,388,608  W1 swizzled bf16 hi
#define OFF_W1L   ((size_t)8388608)    //  8,388,608  W1 swizzled bf16 lo
#define OFF_WHSW  ((size_t)16777216)   //    524,288  Wh swizzled bf16
#define OFF_ENC   ((size_t)17301504)   //  4,194,304  encoder states fp32 [8][512][256]
#define OFF_C     ((size_t)21495808)   //      8,192  c state [8][256]
#define OFF_XSUM  ((size_t)21504000)   //  4,194,304  xs transposed [256][4096]
#define OFF_XPRE  ((size_t)25698304)   // 16,777,216  Xpre [4096][1024]
#define OFF_P1    ((size_t)42475520)   // 33,554,432  split-K partials [8][256][4096]
// Decoder state aliases INTO the P1 region (P1 is dead after k_reduce;
// encoder+decoder run strictly later in stream order):
#define OFF_ENCT  (OFF_P1)                    // 4,194,304  encT [8][256 k][512 t]
#define OFF_HST   (OFF_P1 + (size_t)4194304)  //     8,192  h state [8][256]
#define OFF_CTXG  (OFF_HST + (size_t)8192)    //     8,192  ctx [8][256]
#define OFF_ZG    (OFF_CTXG + (size_t)8192)   //    32,768  z [8][1024]
// total ~76.0 MB (unchanged)

__device__ __forceinline__ unsigned short f2bf(float f) {
  uint32_t u = __float_as_uint(f);
  u += 0x7fffu + ((u >> 16) & 1u);
  return (unsigned short)(u >> 16);
}
__device__ __forceinline__ float bf2f(unsigned short h) {
  return __uint_as_float(((uint32_t)h) << 16);
}
__device__ __forceinline__ float sigm(float x) { return 1.f / (1.f + __expf(-x)); }
__device__ __forceinline__ float tanh_(float x) {
  float ax = fabsf(x);
  float e  = __expf(-2.f * ax);
  float t  = (1.f - e) / (1.f + e);
  return x < 0.f ? -t : t;
}

// ---------------------------------------------------------------------------
// Prep: W1 -> bf16 hi/lo in MFMA A-fragment swizzled layout.
__global__ void k_prep_w1(const float* __restrict__ W1,
                          uint4* __restrict__ hi, uint4* __restrict__ lo) {
  int idx  = blockIdx.x * 1024 + threadIdx.x;     // 0..524287
  int lane = idx & 63;
  int kt   = (idx >> 6) & 511;
  int nt   = idx >> 15;                            // 0..15
  int n    = nt * 16 + (lane & 15);
  int kb   = kt * 32 + ((lane >> 4) << 3);
  unsigned short h8[8], l8[8];
#pragma unroll
  for (int j = 0; j < 8; ++j) {
    float v = W1[(size_t)(kb + j) * 256 + n];
    unsigned short hh = f2bf(v);
    h8[j] = hh;
    l8[j] = f2bf(v - bf2f(hh));
  }
  uint4 uh, ul;
  uh.x = (uint32_t)h8[0] | ((uint32_t)h8[1] << 16);
  uh.y = (uint32_t)h8[2] | ((uint32_t)h8[3] << 16);
  uh.z = (uint32_t)h8[4] | ((uint32_t)h8[5] << 16);
  uh.w = (uint32_t)h8[6] | ((uint32_t)h8[7] << 16);
  ul.x = (uint32_t)l8[0] | ((uint32_t)l8[1] << 16);
  ul.y = (uint32_t)l8[2] | ((uint32_t)l8[3] << 16);
  ul.z = (uint32_t)l8[4] | ((uint32_t)l8[5] << 16);
  ul.w = (uint32_t)l8[6] | ((uint32_t)l8[7] << 16);
  hi[idx] = uh;
  lo[idx] = ul;
}

// Wh -> bf16 swizzled A-fragments. Fragment (zt, kt): m = z col, k = h index.
__global__ void k_prep_wh(const float* __restrict__ Wh, uint4* __restrict__ sw) {
  int idx  = blockIdx.x * 1024 + threadIdx.x;     // 0..32767
  int lane = idx & 63;
  int kt   = (idx >> 6) & 7;
  int zt   = idx >> 9;                             // 0..63
  int col  = zt * 16 + (lane & 15);
  int kb   = kt * 32 + ((lane >> 4) << 3);
  unsigned short h8[8];
#pragma unroll
  for (int j = 0; j < 8; ++j) h8[j] = f2bf(Wh[(size_t)(kb + j) * 1024 + col]);
  uint4 u;
  u.x = (uint32_t)h8[0] | ((uint32_t)h8[1] << 16);
  u.y = (uint32_t)h8[2] | ((uint32_t)h8[3] << 16);
  u.z = (uint32_t)h8[4] | ((uint32_t)h8[5] << 16);
  u.w = (uint32_t)h8[6] | ((uint32_t)h8[7] << 16);
  sw[idx] = u;
}

// ---------------------------------------------------------------------------
// GEMM1 split-K; x-load prefetched one iteration ahead.
__global__ __launch_bounds__(1024)
void k_gemm1(const float* __restrict__ x, const uint4* __restrict__ w1h,
             const uint4* __restrict__ w1l, float* __restrict__ P1) {
  __shared__ __align__(16) unsigned short xh[128 * 40];
  __shared__ __align__(16) unsigned short xl[128 * 40];
  int bm = blockIdx.x >> 3, kc = blockIdx.x & 7;
  int m0 = bm * 128, kcbase = kc * 2048;
  int tid = threadIdx.x, wave = tid >> 6, lane = tid & 63;
  int quad = lane >> 4, l15 = lane & 15;
  int srow = tid >> 3, skch = tid & 7;
  floatx4 acc[8];
#pragma unroll
  for (int mt = 0; mt < 8; ++mt) acc[mt] = (floatx4)(0.f);

  const float* xrow = x + (size_t)(m0 + srow) * K1_ + kcbase + skch * 4;
  float4 xv = *(const float4*)(xrow);
  for (int it = 0; it < 64; ++it) {
    unsigned short h0 = f2bf(xv.x), h1 = f2bf(xv.y), h2 = f2bf(xv.z), h3 = f2bf(xv.w);
    unsigned short g0 = f2bf(xv.x - bf2f(h0)), g1 = f2bf(xv.y - bf2f(h1));
    unsigned short g2 = f2bf(xv.z - bf2f(h2)), g3 = f2bf(xv.w - bf2f(h3));
    uint2 ph, pl;
    ph.x = (uint32_t)h0 | ((uint32_t)h1 << 16); ph.y = (uint32_t)h2 | ((uint32_t)h3 << 16);
    pl.x = (uint32_t)g0 | ((uint32_t)g1 << 16); pl.y = (uint32_t)g2 | ((uint32_t)g3 << 16);
    *(uint2*)&xh[srow * 40 + skch * 4] = ph;
    *(uint2*)&xl[srow * 40 + skch * 4] = pl;
    __syncthreads();

    float4 xn = xv;
    if (it < 63) xn = *(const float4*)(xrow + (it + 1) * 32);

    size_t aoff = (size_t)(wave * 512 + kc * 64 + it) * 64 + lane;
    FragU ah; ah.u = w1h[aoff];
    FragU al; al.u = w1l[aoff];
#pragma unroll
    for (int mt = 0; mt < 8; ++mt) {
      FragU bh, bl;
      bh.u = *(const uint4*)&xh[(mt * 16 + l15) * 40 + quad * 8];
      bl.u = *(const uint4*)&xl[(mt * 16 + l15) * 40 + quad * 8];
      acc[mt] = __builtin_amdgcn_mfma_f32_16x16x32_bf16(ah.s, bh.s, acc[mt], 0, 0, 0);
      acc[mt] = __builtin_amdgcn_mfma_f32_16x16x32_bf16(ah.s, bl.s, acc[mt], 0, 0, 0);
      acc[mt] = __builtin_amdgcn_mfma_f32_16x16x32_bf16(al.s, bh.s, acc[mt], 0, 0, 0);
    }
    __syncthreads();
    xv = xn;
  }
  int nbase = wave * 16 + quad * 4;
#pragma unroll
  for (int mt = 0; mt < 8; ++mt) {
    int m = m0 + mt * 16 + l15;
#pragma unroll
    for (int r = 0; r < 4; ++r)
      P1[(size_t)(kc * 256 + nbase + r) * M_ + m] = acc[mt][r];
  }
}

// Sum split-K partials + b1 -> xsum[k][m]
__global__ void k_reduce(const float* __restrict__ P1, const float* __restrict__ b1,
                         float* __restrict__ xsum) {
  int idx = blockIdx.x * 1024 + threadIdx.x;       // 1,048,576
  int k = idx >> 12, m = idx & 4095;
  float s = b1[k];
#pragma unroll
  for (int kc = 0; kc < 8; ++kc) s += P1[(size_t)(kc * 256 + k) * M_ + m];
  xsum[(size_t)k * M_ + m] = s;
}

// GEMM2 (fp32 VALU)
__global__ __launch_bounds__(256)
void k_gemm2(const float* __restrict__ xsum, const float* __restrict__ Wx,
             const float* __restrict__ bz, float* __restrict__ Xpre) {
  int m0 = blockIdx.x * 16;
  int j = threadIdx.x;
  float acc0[16], acc1[16], acc2[16], acc3[16];
  float bb0 = bz[j], bb1 = bz[256 + j], bb2 = bz[512 + j], bb3 = bz[768 + j];
#pragma unroll
  for (int mm = 0; mm < 16; ++mm) { acc0[mm] = bb0; acc1[mm] = bb1; acc2[mm] = bb2; acc3[mm] = bb3; }
#pragma unroll 4
  for (int k = 0; k < 256; ++k) {
    float w0 = Wx[(size_t)k * 1024 + j];
    float w1 = Wx[(size_t)k * 1024 + 256 + j];
    float w2 = Wx[(size_t)k * 1024 + 512 + j];
    float w3 = Wx[(size_t)k * 1024 + 768 + j];
#pragma unroll
    for (int mm = 0; mm < 16; ++mm) {
      float xv = xsum[(size_t)k * M_ + m0 + mm];
      acc0[mm] += xv * w0; acc1[mm] += xv * w1; acc2[mm] += xv * w2; acc3[mm] += xv * w3;
    }
  }
#pragma unroll
  for (int mm = 0; mm < 16; ++mm) {
    float* o = Xpre + (size_t)(m0 + mm) * 1024;
    o[j] = acc0[mm]; o[256 + j] = acc1[mm]; o[512 + j] = acc2[mm]; o[768 + j] = acc3[mm];
  }
}

// ---------------------------------------------------------------------------
// Encoder v4 (+encT transposed output for the decoder's coalesced scores).
__global__ __launch_bounds__(512, 2)
void k_encoder(const uint4* __restrict__ whsw, const float* __restrict__ Xpre,
               float* __restrict__ enc, float* __restrict__ encT,
               float* __restrict__ cws) {
  __shared__ uint4 wl[8192];
  __shared__ __align__(16) unsigned short hb[2][512];
  __shared__ __align__(16) float zsh[2048];
  int b = blockIdx.x, tid = threadIdx.x;
  int wave = tid >> 6, lane = tid & 63;
  int quad = lane >> 4, l15 = lane & 15;
  int e = tid & 1, j = tid >> 1;

  for (int r = 0; r < 16; ++r) {
    int u = r * 512 + tid;
    int ln = u & 63, fr = u >> 6;
    int w = fr >> 4, G = (fr >> 3) & 1, kt = fr & 7;
    int zt = 16 * (2 * G + 1) + 2 * w + 1;
    wl[u] = whsw[(size_t)((zt * 8 + kt) * 64 + ln)];
  }
  uint4 wfr[48];
#pragma unroll
  for (int G = 0; G < 2; ++G)
#pragma unroll
    for (int i = 0; i < 3; ++i) {
      int zt = 16 * (2 * G + (i >> 1)) + 2 * wave + (i & 1);
#pragma unroll
      for (int kt = 0; kt < 8; ++kt)
        wfr[(G * 3 + i) * 8 + kt] = whsw[(size_t)((zt * 8 + kt) * 64 + lane)];
    }

  hb[0][tid] = 0; hb[1][tid] = 0;
  float c_ = 0.f;
  const float* xpb = Xpre + (size_t)b * 512 * 1024;
  int colA = 256 * e + j;
  int colB = 512 + colA;
  int hoff  = ((l15 == 1) ? 256 : 0) + quad * 8;
  int zwoff = ((l15 == 1) ? 1024 : 0) + quad * 4;
  __syncthreads();

  int cur = 0;
  for (int t = 0; t < 512; ++t) {
    const unsigned short* hbc = hb[cur];
    float xA = xpb[(size_t)t * 1024 + colA];
    float xB = xpb[(size_t)t * 1024 + colB];

#pragma unroll
    for (int G = 0; G < 2; ++G) {
      const uint4* wlg = wl + (size_t)((wave * 2 + G) * 8) * 64 + lane;
      FragU bfr[8], pfr[8];
#pragma unroll
      for (int k = 0; k < 3; ++k) {
        bfr[k].u = *(const uint4*)&hbc[hoff + k * 32];
        pfr[k].u = wlg[(size_t)k * 64];
      }
      floatx4 a0 = (floatx4)(0.f), a1 = (floatx4)(0.f);
      floatx4 a2 = (floatx4)(0.f), a3 = (floatx4)(0.f);
#pragma unroll
      for (int kt = 0; kt < 8; ++kt) {
        if (kt < 5) {
          bfr[kt + 3].u = *(const uint4*)&hbc[hoff + (kt + 3) * 32];
          pfr[kt + 3].u = wlg[(size_t)(kt + 3) * 64];
        }
        FragU f0, f1, f2;
        f0.u = wfr[(G * 3 + 0) * 8 + kt];
        f1.u = wfr[(G * 3 + 1) * 8 + kt];
        f2.u = wfr[(G * 3 + 2) * 8 + kt];
        a0 = __builtin_amdgcn_mfma_f32_16x16x32_bf16(f0.s, bfr[kt].s, a0, 0, 0, 0);
        a1 = __builtin_amdgcn_mfma_f32_16x16x32_bf16(f1.s, bfr[kt].s, a1, 0, 0, 0);
        a2 = __builtin_amdgcn_mfma_f32_16x16x32_bf16(f2.s, bfr[kt].s, a2, 0, 0, 0);
        a3 = __builtin_amdgcn_mfma_f32_16x16x32_bf16(pfr[kt].s, bfr[kt].s, a3, 0, 0, 0);
      }
      if (l15 < 2) {
        int zt0 = 16 * (2 * G) + 2 * wave;
        int zt2 = 16 * (2 * G + 1) + 2 * wave;
        *(floatx4*)&zsh[zwoff + zt0 * 16]        = a0;
        *(floatx4*)&zsh[zwoff + (zt0 + 1) * 16]  = a1;
        *(floatx4*)&zsh[zwoff + zt2 * 16]        = a2;
        *(floatx4*)&zsh[zwoff + (zt2 + 1) * 16]  = a3;
      }
    }

    float zA = zsh[colA] + zsh[1024 + colA] + xA;
    float zB = zsh[colB] + zsh[1024 + colB] + xB;
    float actA = sigm(zA);
    float tnh = tanh_(zB), sg = sigm(zB);
    float actB = e ? sg : tnh;
    float p = actA * actB;
    float send = e ? actA : p;
    float recv = __shfl_xor(send, 1, 64);
    float cn = e ? (actA * c_ + recv)
                 : (recv * c_ + p);
    c_ = cn;
    float th = tanh_(cn);
    float hn = actB * th;
    int nxt = cur ^ 1;
    if (e) {
      enc[((size_t)b * 512 + t) * 256 + j] = hn;
      encT[((size_t)b * 256 + j) * 512 + t] = hn;   // transposed copy for decoder
      unsigned short hh = f2bf(hn);
      hb[nxt][j] = hh;
      hb[nxt][256 + j] = f2bf(hn - bf2f(hh));
    }
    __syncthreads();
    cur = nxt;
  }
  if (e) cws[b * 256 + j] = c_;
}

// ---------------------------------------------------------------------------
// Decoder step kernel A: (optional) LSTM cell from z_{p-1} + output row, then
// q-projection, attention scores (coalesced via encT), softmax, context.
// One block per batch, 1024 threads.
__global__ __launch_bounds__(1024)
void k_dec_att(const float* __restrict__ enc, const float* __restrict__ encT,
               float* __restrict__ hst, float* __restrict__ cst,
               const float* __restrict__ zg, float* __restrict__ ctxg,
               const float* __restrict__ Wa, const float* __restrict__ ba,
               const float* __restrict__ W2, const float* __restrict__ b2,
               float* __restrict__ out, int p) {
  __shared__ float hsh[256], qsh[256], sc[512], smx[2];
  __shared__ float zb[1024];
  int b = blockIdx.x, tid = threadIdx.x;
  const float* encb = enc + (size_t)b * 512 * 256;

  if (p > 0) {
    // LSTM cell from z_{p-1} (bias already folded into zg by k_dec_z)
    if (tid < 256) {
      float zi = zg[b * 1024 + tid];
      float zf = zg[b * 1024 + 256 + tid];
      float zgg = zg[b * 1024 + 512 + tid];
      float zo = zg[b * 1024 + 768 + tid];
      float ig = sigm(zi), fg = sigm(zf), gg = tanh_(zgg), og = sigm(zo);
      float cn = fg * cst[b * 256 + tid] + ig * gg;
      cst[b * 256 + tid] = cn;
      float hn = og * tanh_(cn);
      hsh[tid] = hn;
      hst[b * 256 + tid] = hn;
    }
    __syncthreads();
    // out_{p-1} = h_new @ W2 + b2
    {
      if (tid < 512) {
        int col = tid & 63, kc = tid >> 6;     // kc 0..7
        float s = 0.f;
#pragma unroll
        for (int i = 0; i < 32; ++i) {
          int k = kc * 32 + i;
          s += hsh[k] * W2[(size_t)k * 64 + col];
        }
        zb[tid] = s;
      }
    }
    __syncthreads();
    if (tid < 64) {
      float s = b2[tid];
#pragma unroll
      for (int kc = 0; kc < 8; ++kc) s += zb[kc * 64 + tid];
      out[((size_t)b * 12 + (p - 1)) * 64 + tid] = s;
    }
  } else {
    if (tid < 256) {
      float hv = encb[(size_t)511 * 256 + tid];
      hsh[tid] = hv;
      hst[b * 256 + tid] = hv;
    }
  }
  if (p == 12) return;
  __syncthreads();

  // q = h @ Wa + ba   (k split 4 ways, coalesced over j)
  {
    int j = tid & 255, kc = tid >> 8;          // kc 0..3
    float s = 0.f;
#pragma unroll 8
    for (int i = 0; i < 64; ++i) {
      int k = kc * 64 + i;
      s += hsh[k] * Wa[(size_t)k * 256 + j];
    }
    zb[tid] = s;
  }
  __syncthreads();
  if (tid < 256) qsh[tid] = ba[tid] + zb[tid] + zb[256 + tid] + zb[512 + tid] + zb[768 + tid];
  __syncthreads();

  // scores[hh] = q . enc[hh]  via encT (coalesced over hh, k split 2 ways)
  {
    int hh = tid & 511, kc = tid >> 9;         // kc 0..1
    const float* eT = encT + (size_t)b * 256 * 512;
    float s = 0.f;
#pragma unroll 8
    for (int i = 0; i < 128; ++i) {
      int k = kc * 128 + i;
      s += qsh[k] * eT[(size_t)k * 512 + hh];
    }
    zb[tid] = s;
  }
  __syncthreads();
  if (tid < 512) sc[tid] = zb[tid] + zb[512 + tid];
  __syncthreads();

  // softmax (unnormalized exp; 1/sum applied at ctx)
  if (tid < 64) {
    float m = -3.4e38f;
#pragma unroll
    for (int r = 0; r < 8; ++r) m = fmaxf(m, sc[tid * 8 + r]);
#pragma unroll
    for (int off = 32; off >= 1; off >>= 1) m = fmaxf(m, __shfl_xor(m, off, 64));
    if (tid == 0) smx[0] = m;
  }
  __syncthreads();
  if (tid < 512) sc[tid] = __expf(sc[tid] - smx[0]);
  __syncthreads();
  if (tid < 64) {
    float s = 0.f;
#pragma unroll
    for (int r = 0; r < 8; ++r) s += sc[tid * 8 + r];
#pragma unroll
    for (int off = 32; off >= 1; off >>= 1) s += __shfl_xor(s, off, 64);
    if (tid == 0) smx[1] = 1.f / s;
  }
  __syncthreads();

  // ctx = softmax . enc   (hh split 4 ways, coalesced over j)
  {
    int j = tid & 255, hs = tid >> 8;          // hs 0..3
    float s = 0.f;
#pragma unroll 8
    for (int r = 0; r < 128; ++r) {
      int hh = hs * 128 + r;
      s += sc[hh] * encb[(size_t)hh * 256 + j];
    }
    zb[tid] = s;
  }
  __syncthreads();
  if (tid < 256)
    ctxg[b * 256 + tid] = (zb[tid] + zb[256 + tid] + zb[512 + tid] + zb[768 + tid]) * smx[1];
}

// ---------------------------------------------------------------------------
// Decoder step kernel B: z = ctx@Wx + h@Wh + bz, split over 8 N-chunks x 8
// batches (64 blocks x 512 threads). Each block streams only 256 KB of
// weights; 64 CUs run concurrently.
__global__ __launch_bounds__(512)
void k_dec_z(const float* __restrict__ ctxg, const float* __restrict__ hst,
             const float* __restrict__ Wx, const float* __restrict__ Wh,
             const float* __restrict__ bz, float* __restrict__ zg) {
  __shared__ float ldsx[256], ldsh[256], zsh[512];
  int chunk = blockIdx.x & 7, b = blockIdx.x >> 3;
  int tid = threadIdx.x;
  int j = tid & 127, ks = (tid >> 7) & 1, sel = tid >> 8;
  int col = chunk * 128 + j;

  if (tid < 256) ldsx[tid] = ctxg[b * 256 + tid];
  else ldsh[tid - 256] = hst[b * 256 + (tid - 256)];
  __syncthreads();

  const float* W = sel ? Wh : Wx;
  const float* v = sel ? ldsh : ldsx;
  float s = 0.f;
#pragma unroll 8
  for (int i = 0; i < 128; ++i) {
    int k = ks * 128 + i;
    s += v[k] * W[(size_t)k * 1024 + col];
  }
  zsh[tid] = s;
  __syncthreads();
  if (tid < 128)
    zg[b * 1024 + col] = bz[col] + zsh[j] + zsh[128 + j] + zsh[256 + j] + zsh[384 + j];
}

// ---------------------------------------------------------------------------
extern "C" void kernel_launch(void* const* d_in, const int* in_sizes, int n_in,
                              void* d_out, int out_size, void* d_ws, size_t ws_size,
                              hipStream_t stream) {
  const float* x  = (const float*)d_in[0];
  const float* W1 = (const float*)d_in[1];
  const float* b1 = (const float*)d_in[2];
  const float* Wx = (const float*)d_in[3];
  const float* Wh = (const float*)d_in[4];
  const float* bz = (const float*)d_in[5];
  const float* Wa = (const float*)d_in[6];
  const float* ba = (const float*)d_in[7];
  const float* W2 = (const float*)d_in[8];
  const float* b2 = (const float*)d_in[9];

  char* ws = (char*)d_ws;
  uint4* w1h  = (uint4*)(ws + OFF_W1H);
  uint4* w1l  = (uint4*)(ws + OFF_W1L);
  uint4* whsw = (uint4*)(ws + OFF_WHSW);
  float* enc  = (float*)(ws + OFF_ENC);
  float* cws  = (float*)(ws + OFF_C);
  float* xsum = (float*)(ws + OFF_XSUM);
  float* xpre = (float*)(ws + OFF_XPRE);
  float* p1   = (float*)(ws + OFF_P1);
  float* encT = (float*)(ws + OFF_ENCT);
  float* hst  = (float*)(ws + OFF_HST);
  float* ctxg = (float*)(ws + OFF_CTXG);
  float* zg   = (float*)(ws + OFF_ZG);

  k_prep_w1<<<dim3(512), dim3(1024), 0, stream>>>(W1, w1h, w1l);
  k_prep_wh<<<dim3(32), dim3(1024), 0, stream>>>(Wh, whsw);
  k_gemm1<<<dim3(256), dim3(1024), 0, stream>>>(x, w1h, w1l, p1);
  k_reduce<<<dim3(1024), dim3(1024), 0, stream>>>(p1, b1, xsum);
  k_gemm2<<<dim3(256), dim3(256), 0, stream>>>(xsum, Wx, bz, xpre);
  k_encoder<<<dim3(8), dim3(512), 0, stream>>>(whsw, xpre, enc, encT, cws);
  for (int p = 0; p <= 12; ++p) {
    k_dec_att<<<dim3(8), dim3(1024), 0, stream>>>(enc, encT, hst, cws, zg, ctxg,
                                                  Wa, ba, W2, b2, (float*)d_out, p);
    if (p < 12)
      k_dec_z<<<dim3(64), dim3(512), 0, stream>>>(ctxg, hst, Wx, Wh, bz, zg);
  }
}

// Round 6
// 1941.845 us; speedup vs baseline: 1.6483x; 1.0241x over previous
//
#include <hip/hip_runtime.h>
#include <hip/hip_bf16.h>
#include <stdint.h>

// Problem constants
#define B_ 8
#define H_ 512
#define F_ 256
#define P_ 12
#define M_ 4096          // B*H
#define K1_ 16384        // N*F = 64*256
#define J_ 1024          // 4*F

typedef __attribute__((ext_vector_type(8))) short short8;
typedef __attribute__((ext_vector_type(4))) float floatx4;

union FragU { uint4 u; short8 s; };

// Workspace layout (bytes)
#define OFF_W1H   ((size_t)0)          //  8,388,608  W1 swizzled bf16 hi
#define OFF_W1L   ((size_t)8388608)    //  8,388,608  W1 swizzled bf16 lo
#define OFF_WHSW  ((size_t)16777216)   //    524,288  Wh swizzled bf16
#define OFF_ENC   ((size_t)17301504)   //  4,194,304  encoder states fp32 [8][512][256]
#define OFF_C     ((size_t)21495808)   //      8,192  c state [8][256]
#define OFF_XSUM  ((size_t)21504000)   //  4,194,304  xs transposed [256][4096]
#define OFF_XPRE  ((size_t)25698304)   // 16,777,216  Xpre [4096][1024]
#define OFF_P1    ((size_t)42475520)   // 33,554,432  split-K partials [8][256][4096]
// Decoder state aliases INTO the P1 region (P1 dead after k_reduce):
#define OFF_ENCT  (OFF_P1)                    // 4,194,304  encT [8][256 k][512 t]
#define OFF_ZG    (OFF_ENCT + (size_t)4194304) //   32,768  z [8][1024]

__device__ __forceinline__ unsigned short f2bf(float f) {
  uint32_t u = __float_as_uint(f);
  u += 0x7fffu + ((u >> 16) & 1u);
  return (unsigned short)(u >> 16);
}
__device__ __forceinline__ float bf2f(unsigned short h) {
  return __uint_as_float(((uint32_t)h) << 16);
}
__device__ __forceinline__ float sigm(float x) { return 1.f / (1.f + __expf(-x)); }
__device__ __forceinline__ float tanh_(float x) {
  float ax = fabsf(x);
  float e  = __expf(-2.f * ax);
  float t  = (1.f - e) / (1.f + e);
  return x < 0.f ? -t : t;
}

// ---------------------------------------------------------------------------
// Prep: W1 -> bf16 hi/lo in MFMA A-fragment swizzled layout.
__global__ void k_prep_w1(const float* __restrict__ W1,
                          uint4* __restrict__ hi, uint4* __restrict__ lo) {
  int idx  = blockIdx.x * 1024 + threadIdx.x;     // 0..524287
  int lane = idx & 63;
  int kt   = (idx >> 6) & 511;
  int nt   = idx >> 15;                            // 0..15
  int n    = nt * 16 + (lane & 15);
  int kb   = kt * 32 + ((lane >> 4) << 3);
  unsigned short h8[8], l8[8];
#pragma unroll
  for (int j = 0; j < 8; ++j) {
    float v = W1[(size_t)(kb + j) * 256 + n];
    unsigned short hh = f2bf(v);
    h8[j] = hh;
    l8[j] = f2bf(v - bf2f(hh));
  }
  uint4 uh, ul;
  uh.x = (uint32_t)h8[0] | ((uint32_t)h8[1] << 16);
  uh.y = (uint32_t)h8[2] | ((uint32_t)h8[3] << 16);
  uh.z = (uint32_t)h8[4] | ((uint32_t)h8[5] << 16);
  uh.w = (uint32_t)h8[6] | ((uint32_t)h8[7] << 16);
  ul.x = (uint32_t)l8[0] | ((uint32_t)l8[1] << 16);
  ul.y = (uint32_t)l8[2] | ((uint32_t)l8[3] << 16);
  ul.z = (uint32_t)l8[4] | ((uint32_t)l8[5] << 16);
  ul.w = (uint32_t)l8[6] | ((uint32_t)l8[7] << 16);
  hi[idx] = uh;
  lo[idx] = ul;
}

// Wh -> bf16 swizzled A-fragments. Fragment (zt, kt): m = z col, k = h index.
__global__ void k_prep_wh(const float* __restrict__ Wh, uint4* __restrict__ sw) {
  int idx  = blockIdx.x * 1024 + threadIdx.x;     // 0..32767
  int lane = idx & 63;
  int kt   = (idx >> 6) & 7;
  int zt   = idx >> 9;                             // 0..63
  int col  = zt * 16 + (lane & 15);
  int kb   = kt * 32 + ((lane >> 4) << 3);
  unsigned short h8[8];
#pragma unroll
  for (int j = 0; j < 8; ++j) h8[j] = f2bf(Wh[(size_t)(kb + j) * 1024 + col]);
  uint4 u;
  u.x = (uint32_t)h8[0] | ((uint32_t)h8[1] << 16);
  u.y = (uint32_t)h8[2] | ((uint32_t)h8[3] << 16);
  u.z = (uint32_t)h8[4] | ((uint32_t)h8[5] << 16);
  u.w = (uint32_t)h8[6] | ((uint32_t)h8[7] << 16);
  sw[idx] = u;
}

// ---------------------------------------------------------------------------
// GEMM1 split-K (unchanged)
__global__ __launch_bounds__(1024)
void k_gemm1(const float* __restrict__ x, const uint4* __restrict__ w1h,
             const uint4* __restrict__ w1l, float* __restrict__ P1) {
  __shared__ __align__(16) unsigned short xh[128 * 40];
  __shared__ __align__(16) unsigned short xl[128 * 40];
  int bm = blockIdx.x >> 3, kc = blockIdx.x & 7;
  int m0 = bm * 128, kcbase = kc * 2048;
  int tid = threadIdx.x, wave = tid >> 6, lane = tid & 63;
  int quad = lane >> 4, l15 = lane & 15;
  int srow = tid >> 3, skch = tid & 7;
  floatx4 acc[8];
#pragma unroll
  for (int mt = 0; mt < 8; ++mt) acc[mt] = (floatx4)(0.f);

  const float* xrow = x + (size_t)(m0 + srow) * K1_ + kcbase + skch * 4;
  float4 xv = *(const float4*)(xrow);
  for (int it = 0; it < 64; ++it) {
    unsigned short h0 = f2bf(xv.x), h1 = f2bf(xv.y), h2 = f2bf(xv.z), h3 = f2bf(xv.w);
    unsigned short g0 = f2bf(xv.x - bf2f(h0)), g1 = f2bf(xv.y - bf2f(h1));
    unsigned short g2 = f2bf(xv.z - bf2f(h2)), g3 = f2bf(xv.w - bf2f(h3));
    uint2 ph, pl;
    ph.x = (uint32_t)h0 | ((uint32_t)h1 << 16); ph.y = (uint32_t)h2 | ((uint32_t)h3 << 16);
    pl.x = (uint32_t)g0 | ((uint32_t)g1 << 16); pl.y = (uint32_t)g2 | ((uint32_t)g3 << 16);
    *(uint2*)&xh[srow * 40 + skch * 4] = ph;
    *(uint2*)&xl[srow * 40 + skch * 4] = pl;
    __syncthreads();

    float4 xn = xv;
    if (it < 63) xn = *(const float4*)(xrow + (it + 1) * 32);

    size_t aoff = (size_t)(wave * 512 + kc * 64 + it) * 64 + lane;
    FragU ah; ah.u = w1h[aoff];
    FragU al; al.u = w1l[aoff];
#pragma unroll
    for (int mt = 0; mt < 8; ++mt) {
      FragU bh, bl;
      bh.u = *(const uint4*)&xh[(mt * 16 + l15) * 40 + quad * 8];
      bl.u = *(const uint4*)&xl[(mt * 16 + l15) * 40 + quad * 8];
      acc[mt] = __builtin_amdgcn_mfma_f32_16x16x32_bf16(ah.s, bh.s, acc[mt], 0, 0, 0);
      acc[mt] = __builtin_amdgcn_mfma_f32_16x16x32_bf16(ah.s, bl.s, acc[mt], 0, 0, 0);
      acc[mt] = __builtin_amdgcn_mfma_f32_16x16x32_bf16(al.s, bh.s, acc[mt], 0, 0, 0);
    }
    __syncthreads();
    xv = xn;
  }
  int nbase = wave * 16 + quad * 4;
#pragma unroll
  for (int mt = 0; mt < 8; ++mt) {
    int m = m0 + mt * 16 + l15;
#pragma unroll
    for (int r = 0; r < 4; ++r)
      P1[(size_t)(kc * 256 + nbase + r) * M_ + m] = acc[mt][r];
  }
}

// Sum split-K partials + b1 -> xsum[k][m]
__global__ void k_reduce(const float* __restrict__ P1, const float* __restrict__ b1,
                         float* __restrict__ xsum) {
  int idx = blockIdx.x * 1024 + threadIdx.x;       // 1,048,576
  int k = idx >> 12, m = idx & 4095;
  float s = b1[k];
#pragma unroll
  for (int kc = 0; kc < 8; ++kc) s += P1[(size_t)(kc * 256 + k) * M_ + m];
  xsum[(size_t)k * M_ + m] = s;
}

// GEMM2 (fp32 VALU)
__global__ __launch_bounds__(256)
void k_gemm2(const float* __restrict__ xsum, const float* __restrict__ Wx,
             const float* __restrict__ bz, float* __restrict__ Xpre) {
  int m0 = blockIdx.x * 16;
  int j = threadIdx.x;
  float acc0[16], acc1[16], acc2[16], acc3[16];
  float bb0 = bz[j], bb1 = bz[256 + j], bb2 = bz[512 + j], bb3 = bz[768 + j];
#pragma unroll
  for (int mm = 0; mm < 16; ++mm) { acc0[mm] = bb0; acc1[mm] = bb1; acc2[mm] = bb2; acc3[mm] = bb3; }
#pragma unroll 4
  for (int k = 0; k < 256; ++k) {
    float w0 = Wx[(size_t)k * 1024 + j];
    float w1 = Wx[(size_t)k * 1024 + 256 + j];
    float w2 = Wx[(size_t)k * 1024 + 512 + j];
    float w3 = Wx[(size_t)k * 1024 + 768 + j];
#pragma unroll
    for (int mm = 0; mm < 16; ++mm) {
      float xv = xsum[(size_t)k * M_ + m0 + mm];
      acc0[mm] += xv * w0; acc1[mm] += xv * w1; acc2[mm] += xv * w2; acc3[mm] += xv * w3;
    }
  }
#pragma unroll
  for (int mm = 0; mm < 16; ++mm) {
    float* o = Xpre + (size_t)(m0 + mm) * 1024;
    o[j] = acc0[mm]; o[256 + j] = acc1[mm]; o[512 + j] = acc2[mm]; o[768 + j] = acc3[mm];
  }
}

// ---------------------------------------------------------------------------
// Encoder v7: 512 threads (8 waves), INTRINSIC MFMAs (proven lineage), with
// amdgpu_waves_per_eu(2,2) pinning EXACTLY 2 waves/SIMD -> the allocator gets
// the full 256-reg/wave budget instead of voluntarily targeting 4 waves/EU
// and spilling the weight array to scratch (round-3's VGPR_Count=128 tell).
//   - 46 weight frags/wave in VGPRs (184 regs), 18/wave streamed from LDS
//     (144 KB). Working set kept ~50 regs via 1-deep prefetch. Total ~250.
//   - Wave-local z tiles (zt = 16*(i>>1) + 2*w + (i&1)), one barrier/step.
__global__ __attribute__((amdgpu_flat_work_group_size(512, 512)))
__attribute__((amdgpu_waves_per_eu(2, 2)))
void k_encoder(const uint4* __restrict__ whsw, const float* __restrict__ Xpre,
               float* __restrict__ enc, float* __restrict__ encT,
               float* __restrict__ cws) {
  __shared__ uint4 wl[9216];                          // 144 KB LDS weight frags
  __shared__ __align__(16) unsigned short hb[2][512]; // dbuf h hi/lo
  __shared__ __align__(16) float zsh[2048];
  int b = blockIdx.x, tid = threadIdx.x;
  int wave = tid >> 6, lane = tid & 63;
  int quad = lane >> 4, l15 = lane & 15;
  int e = tid & 1, j = tid >> 1;

  // stage wl: per wave 18 frags: fi 0..7 = tile i6 kt; 8..15 = i7 kt; 16..17 = i5 kt6,7
  for (int r = 0; r < 18; ++r) {
    int u = r * 512 + tid;                 // 0..9215
    int ln = u & 63, fslot = u >> 6;       // 0..143
    int w = fslot / 18, fi = fslot - w * 18;
    int i = (fi < 8) ? 6 : ((fi < 16) ? 7 : 5);
    int kt = (fi < 8) ? fi : ((fi < 16) ? fi - 8 : fi - 10);
    int zt = 16 * (i >> 1) + 2 * w + (i & 1);
    wl[u] = whsw[(size_t)((zt * 8 + kt) * 64 + ln)];
  }

  // Register-resident weights: tiles i0..4 all kt (40) + i5 kt0..5 (6)
  uint4 wfr[46];
#pragma unroll
  for (int i = 0; i < 5; ++i) {
    int zt = 16 * (i >> 1) + 2 * wave + (i & 1);
#pragma unroll
    for (int kt = 0; kt < 8; ++kt)
      wfr[i * 8 + kt] = whsw[(size_t)((zt * 8 + kt) * 64 + lane)];
  }
  {
    int zt = 33 + 2 * wave;                // i = 5
#pragma unroll
    for (int kt = 0; kt < 6; ++kt)
      wfr[40 + kt] = whsw[(size_t)((zt * 8 + kt) * 64 + lane)];
  }

  hb[0][tid] = 0; hb[1][tid] = 0;
  float c_ = 0.f;
  const float* xpb = Xpre + (size_t)b * 512 * 1024;
  int colA = 256 * e + j;
  int colB = 512 + colA;
  int hoff  = ((l15 == 1) ? 256 : 0) + quad * 8;
  int zwoff = ((l15 == 1) ? 1024 : 0) + quad * 4;
  const uint4* wlw = wl + (size_t)(wave * 18) * 64 + lane;
  __syncthreads();

  int cur = 0;
  for (int t = 0; t < 512; ++t) {
    const unsigned short* hbc = hb[cur];
    float xA = xpb[(size_t)t * 1024 + colA];
    float xB = xpb[(size_t)t * 1024 + colB];

    // ---- G0: tiles i0..i3 (all register-resident) ----
    {
      floatx4 a0 = (floatx4)(0.f), a1 = (floatx4)(0.f);
      floatx4 a2 = (floatx4)(0.f), a3 = (floatx4)(0.f);
      FragU bf; bf.u = *(const uint4*)&hbc[hoff];
#pragma unroll
      for (int kt = 0; kt < 8; ++kt) {
        FragU bfn;
        if (kt < 7) bfn.u = *(const uint4*)&hbc[hoff + (kt + 1) * 32];
        FragU f0, f1, f2, f3;
        f0.u = wfr[0 + kt];  f1.u = wfr[8 + kt];
        f2.u = wfr[16 + kt]; f3.u = wfr[24 + kt];
        a0 = __builtin_amdgcn_mfma_f32_16x16x32_bf16(f0.s, bf.s, a0, 0, 0, 0);
        a1 = __builtin_amdgcn_mfma_f32_16x16x32_bf16(f1.s, bf.s, a1, 0, 0, 0);
        a2 = __builtin_amdgcn_mfma_f32_16x16x32_bf16(f2.s, bf.s, a2, 0, 0, 0);
        a3 = __builtin_amdgcn_mfma_f32_16x16x32_bf16(f3.s, bf.s, a3, 0, 0, 0);
        if (kt < 7) bf = bfn;
      }
      if (l15 < 2) {
        *(floatx4*)&zsh[zwoff + (2 * wave) * 16]      = a0;
        *(floatx4*)&zsh[zwoff + (2 * wave + 1) * 16]  = a1;
        *(floatx4*)&zsh[zwoff + (16 + 2 * wave) * 16] = a2;
        *(floatx4*)&zsh[zwoff + (17 + 2 * wave) * 16] = a3;
      }
    }
    // ---- G1: i4 (regs), i5 (regs kt<6 / LDS kt>=6), i6,i7 (LDS) ----
    {
      floatx4 a4 = (floatx4)(0.f), a5 = (floatx4)(0.f);
      floatx4 a6 = (floatx4)(0.f), a7 = (floatx4)(0.f);
      FragU p5a, p5b;
      p5a.u = wlw[(size_t)16 * 64];
      p5b.u = wlw[(size_t)17 * 64];
      FragU bf, p6, p7;
      bf.u = *(const uint4*)&hbc[hoff];
      p6.u = wlw[0];
      p7.u = wlw[(size_t)8 * 64];
#pragma unroll
      for (int kt = 0; kt < 8; ++kt) {
        FragU bfn, p6n, p7n;
        if (kt < 7) {
          bfn.u = *(const uint4*)&hbc[hoff + (kt + 1) * 32];
          p6n.u = wlw[(size_t)(kt + 1) * 64];
          p7n.u = wlw[(size_t)(9 + kt) * 64];
        }
        FragU f4; f4.u = wfr[32 + kt];
        a4 = __builtin_amdgcn_mfma_f32_16x16x32_bf16(f4.s, bf.s, a4, 0, 0, 0);
        if (kt < 6) {
          FragU f5; f5.u = wfr[40 + kt];
          a5 = __builtin_amdgcn_mfma_f32_16x16x32_bf16(f5.s, bf.s, a5, 0, 0, 0);
        } else if (kt == 6) {
          a5 = __builtin_amdgcn_mfma_f32_16x16x32_bf16(p5a.s, bf.s, a5, 0, 0, 0);
        } else {
          a5 = __builtin_amdgcn_mfma_f32_16x16x32_bf16(p5b.s, bf.s, a5, 0, 0, 0);
        }
        a6 = __builtin_amdgcn_mfma_f32_16x16x32_bf16(p6.s, bf.s, a6, 0, 0, 0);
        a7 = __builtin_amdgcn_mfma_f32_16x16x32_bf16(p7.s, bf.s, a7, 0, 0, 0);
        if (kt < 7) { bf = bfn; p6 = p6n; p7 = p7n; }
      }
      if (l15 < 2) {
        *(floatx4*)&zsh[zwoff + (32 + 2 * wave) * 16] = a4;
        *(floatx4*)&zsh[zwoff + (33 + 2 * wave) * 16] = a5;
        *(floatx4*)&zsh[zwoff + (48 + 2 * wave) * 16] = a6;
        *(floatx4*)&zsh[zwoff + (49 + 2 * wave) * 16] = a7;
      }
    }

    // gates: paired even/odd lanes; z from this wave's own tiles
    float zA = zsh[colA] + zsh[1024 + colA] + xA;
    float zB = zsh[colB] + zsh[1024 + colB] + xB;
    float actA = sigm(zA);                       // i (even) / f (odd)
    float tnh = tanh_(zB), sg = sigm(zB);
    float actB = e ? sg : tnh;                   // g (even) / o (odd)
    float p = actA * actB;
    float send = e ? actA : p;
    float recv = __shfl_xor(send, 1, 64);
    float cn = e ? (actA * c_ + recv)
                 : (recv * c_ + p);
    c_ = cn;
    float th = tanh_(cn);
    float hn = actB * th;                        // odd lane: o*tanh(c)
    int nxt = cur ^ 1;
    if (e) {
      enc[((size_t)b * 512 + t) * 256 + j] = hn;
      encT[((size_t)b * 256 + j) * 512 + t] = hn;
      unsigned short hh = f2bf(hn);
      hb[nxt][j] = hh;
      hb[nxt][256 + j] = f2bf(hn - bf2f(hh));
    }
    __syncthreads();
    cur = nxt;
  }
  if (e) cws[b * 256 + j] = c_;
}

// ---------------------------------------------------------------------------
// Decoder merged step: attention + cell + out + z-GEMV in one kernel.
// 8 blocks (one per batch), 1024 threads, 13 launches total.
__global__ __launch_bounds__(1024)
void k_dec_step(const float* __restrict__ enc, const float* __restrict__ encT,
                float* __restrict__ cst, float* __restrict__ zg,
                const float* __restrict__ Wx, const float* __restrict__ Wh,
                const float* __restrict__ bz,
                const float* __restrict__ Wa, const float* __restrict__ ba,
                const float* __restrict__ W2, const float* __restrict__ b2,
                float* __restrict__ out, int p) {
  __shared__ float hsh[256], qsh[256], ctxs[256], sc[512], smx[2];
  __shared__ float zb[1024];
  int b = blockIdx.x, tid = threadIdx.x;
  const float* encb = enc + (size_t)b * 512 * 256;

  if (p > 0) {
    // LSTM cell from z_{p-1} (bias folded into zg)
    if (tid < 256) {
      float zi = zg[b * 1024 + tid];
      float zf = zg[b * 1024 + 256 + tid];
      float zgg = zg[b * 1024 + 512 + tid];
      float zo = zg[b * 1024 + 768 + tid];
      float ig = sigm(zi), fg = sigm(zf), gg = tanh_(zgg), og = sigm(zo);
      float cn = fg * cst[b * 256 + tid] + ig * gg;
      cst[b * 256 + tid] = cn;
      hsh[tid] = og * tanh_(cn);
    }
    __syncthreads();
    if (tid < 512) {
      int col = tid & 63, kc = tid >> 6;     // kc 0..7
      float s = 0.f;
#pragma unroll
      for (int i = 0; i < 32; ++i) {
        int k = kc * 32 + i;
        s += hsh[k] * W2[(size_t)k * 64 + col];
      }
      zb[tid] = s;
    }
    __syncthreads();
    if (tid < 64) {
      float s = b2[tid];
#pragma unroll
      for (int kc = 0; kc < 8; ++kc) s += zb[kc * 64 + tid];
      out[((size_t)b * 12 + (p - 1)) * 64 + tid] = s;
    }
  } else {
    if (tid < 256) hsh[tid] = encb[(size_t)511 * 256 + tid];
  }
  if (p == 12) return;
  __syncthreads();

  // q = h @ Wa + ba  (k split 4 ways)
  {
    int jj = tid & 255, kc = tid >> 8;
    float s = 0.f;
#pragma unroll 8
    for (int i = 0; i < 64; ++i) {
      int k = kc * 64 + i;
      s += hsh[k] * Wa[(size_t)k * 256 + jj];
    }
    zb[tid] = s;
  }
  __syncthreads();
  if (tid < 256) qsh[tid] = ba[tid] + zb[tid] + zb[256 + tid] + zb[512 + tid] + zb[768 + tid];
  __syncthreads();

  // scores via encT (coalesced over hh, k split 2 ways)
  {
    int hh = tid & 511, kc = tid >> 9;
    const float* eT = encT + (size_t)b * 256 * 512;
    float s = 0.f;
#pragma unroll 8
    for (int i = 0; i < 128; ++i) {
      int k = kc * 128 + i;
      s += qsh[k] * eT[(size_t)k * 512 + hh];
    }
    zb[tid] = s;
  }
  __syncthreads();
  if (tid < 512) sc[tid] = zb[tid] + zb[512 + tid];
  __syncthreads();

  if (tid < 64) {
    float m = -3.4e38f;
#pragma unroll
    for (int r = 0; r < 8; ++r) m = fmaxf(m, sc[tid * 8 + r]);
#pragma unroll
    for (int off = 32; off >= 1; off >>= 1) m = fmaxf(m, __shfl_xor(m, off, 64));
    if (tid == 0) smx[0] = m;
  }
  __syncthreads();
  if (tid < 512) sc[tid] = __expf(sc[tid] - smx[0]);
  __syncthreads();
  if (tid < 64) {
    float s = 0.f;
#pragma unroll
    for (int r = 0; r < 8; ++r) s += sc[tid * 8 + r];
#pragma unroll
    for (int off = 32; off >= 1; off >>= 1) s += __shfl_xor(s, off, 64);
    if (tid == 0) smx[1] = 1.f / s;
  }
  __syncthreads();

  // ctx = softmax . enc  (hh split 4 ways)
  {
    int jj = tid & 255, hs = tid >> 8;
    float s = 0.f;
#pragma unroll 8
    for (int r = 0; r < 128; ++r) {
      int hh = hs * 128 + r;
      s += sc[hh] * encb[(size_t)hh * 256 + jj];
    }
    zb[tid] = s;
  }
  __syncthreads();
  if (tid < 256)
    ctxs[tid] = (zb[tid] + zb[256 + tid] + zb[512 + tid] + zb[768 + tid]) * smx[1];
  __syncthreads();

  // z = ctx@Wx + h@Wh + bz  (one col per thread)
  {
    float s = bz[tid];
#pragma unroll 16
    for (int k = 0; k < 256; ++k)
      s += ctxs[k] * Wx[(size_t)k * 1024 + tid] + hsh[k] * Wh[(size_t)k * 1024 + tid];
    zg[b * 1024 + tid] = s;
  }
}

// ---------------------------------------------------------------------------
extern "C" void kernel_launch(void* const* d_in, const int* in_sizes, int n_in,
                              void* d_out, int out_size, void* d_ws, size_t ws_size,
                              hipStream_t stream) {
  const float* x  = (const float*)d_in[0];
  const float* W1 = (const float*)d_in[1];
  const float* b1 = (const float*)d_in[2];
  const float* Wx = (const float*)d_in[3];
  const float* Wh = (const float*)d_in[4];
  const float* bz = (const float*)d_in[5];
  const float* Wa = (const float*)d_in[6];
  const float* ba = (const float*)d_in[7];
  const float* W2 = (const float*)d_in[8];
  const float* b2 = (const float*)d_in[9];

  char* ws = (char*)d_ws;
  uint4* w1h  = (uint4*)(ws + OFF_W1H);
  uint4* w1l  = (uint4*)(ws + OFF_W1L);
  uint4* whsw = (uint4*)(ws + OFF_WHSW);
  float* enc  = (float*)(ws + OFF_ENC);
  float* cws  = (float*)(ws + OFF_C);
  float* xsum = (float*)(ws + OFF_XSUM);
  float* xpre = (float*)(ws + OFF_XPRE);
  float* p1   = (float*)(ws + OFF_P1);
  float* encT = (float*)(ws + OFF_ENCT);
  float* zg   = (float*)(ws + OFF_ZG);

  k_prep_w1<<<dim3(512), dim3(1024), 0, stream>>>(W1, w1h, w1l);
  k_prep_wh<<<dim3(32), dim3(1024), 0, stream>>>(Wh, whsw);
  k_gemm1<<<dim3(256), dim3(1024), 0, stream>>>(x, w1h, w1l, p1);
  k_reduce<<<dim3(1024), dim3(1024), 0, stream>>>(p1, b1, xsum);
  k_gemm2<<<dim3(256), dim3(256), 0, stream>>>(xsum, Wx, bz, xpre);
  k_encoder<<<dim3(8), dim3(512), 0, stream>>>(whsw, xpre, enc, encT, cws);
  for (int p = 0; p <= 12; ++p)
    k_dec_step<<<dim3(8), dim3(1024), 0, stream>>>(enc, encT, cws, zg,
                                                   Wx, Wh, bz, Wa, ba, W2, b2,
                                                   (float*)d_out, p);
}